// Round 6
// baseline (22533.403 us; speedup 1.0000x reference)
//
#include <hip/hip_runtime.h>
#include <cstddef>

// ---------------------------------------------------------------------------
// RNN_Reverser round 5 (resubmit — round-5 bench was a GPU-acquisition
// timeout, no data): 3-stage layer pipeline.
//   gemm: P_e0 = X @ W_e0^T + b (K=131); later P_d0 likewise.
//   pipe_kernel (48 blocks, 512 thr):
//     role0 (bid 0-15):  L0 scan (round-3 structure, packed-u32 LDS state),
//                        publishes h0_t tiles to xring (+flag, fence).
//     role1 (bid 16-31): p1_t = h0_t @ W1^T + b1 (no recurrence, no barriers,
//                        per-wave output flags), publishes to p1ring.
//     role2 (bid 32-47): L1 scan consuming p1ring (round-3 structure).
//   Pipeline replaces scan+gemm(K=256)+scan per encoder/decoder pair.
//   Cross-block sync: device-scope atomic flags + __threadfence release/acquire
//   (cross-XCD safe); cached flags make fences rare; polls capped (no hang).
//   Rings (64MB each) + counters live in buf1; decoder L1 output overwrites
//   consumed P_d0 in buf0 in place (D1 at step t strictly after D0 read t+1).
// Round-4 lessons kept: 512 thr / 2 waves/SIMD is load-bearing; packed-u32
// state (proven correct, conflicts halved) with perm unpack.
// All matmuls split-bf16 (hh+hl+lh) for fp32-like precision.
// ---------------------------------------------------------------------------

typedef __attribute__((ext_vector_type(8))) short short8;
typedef __attribute__((ext_vector_type(4))) float f32x4;

namespace {
constexpr int TSTEPS = 1023;
constexpr int BATCH = 256;
constexpr int IND = 131;
constexpr int OUTD = 131;
constexpr int MTOT = TSTEPS * BATCH;  // 261888
constexpr int RING = 256;             // handoff ring slots per group
constexpr int POLLCAP = 8192;         // spin cap per wait site (no-hang)

// fast path ws layout (bytes)
constexpr size_t SB = (size_t)MTOT * 256 * 4;  // 268,173,312 one P buffer
// pack region: ushort offsets
constexpr int UE0 = 0;        // each U pack: hi 65536 + lo 65536
constexpr int UE1 = 131072;
constexpr int UD0 = 262144;
constexpr int UD1 = 393216;
constexpr int EW0 = 524288;   // proj K=131: hi 40960 + lo 40960
constexpr int DW0 = 606208;
constexpr int EW1 = 688128;   // proj K=256: hi 65536 + lo 65536
constexpr int DW1 = 819200;
constexpr int LINP = 950272;  // lin: hi 36864 + lo 36864
constexpr int PK_USH = 1024000;
constexpr size_t PKB = 2 * SB;                   // pack base (bytes)
constexpr size_t BFB = PKB + 2 * (size_t)PK_USH; // bias/finals float region
constexpr int FIN0 = 1168;
constexpr int FIN1 = 1168 + 65536;
constexpr size_t TOTAL_WS = BFB + (size_t)(1168 + 2 * 65536) * 4;  // 538,923,584

// slow path (round 1) float offsets
constexpr int OFF_EW0s = 0, OFF_EH0s = 33792, OFF_EW1s = 99328, OFF_EH1s = 164864;
constexpr int OFF_DW0s = 230400, OFF_DH0s = 264192, OFF_DW1s = 329728, OFF_DH1s = 395264;
constexpr int OFF_LWs = 460800, OFF_EB0s = 494336, OFF_EB1s = 494592;
constexpr int OFF_DB0s = 494848, OFF_DB1s = 495104;
constexpr int WS_TOTAL_SLOW = 495360;
}  // namespace

__device__ __forceinline__ unsigned short f2bf(float x) {
  unsigned u = __float_as_uint(x);
  u += 0x7fffu + ((u >> 16) & 1u);
  return (unsigned short)(u >> 16);
}
__device__ __forceinline__ float bf2f(unsigned short h) {
  return __uint_as_float(((unsigned)h) << 16);
}
__device__ __forceinline__ unsigned packbf(float x) {
  const unsigned short h = f2bf(x);
  const unsigned short l = f2bf(x - bf2f(h));
  return ((unsigned)l << 16) | (unsigned)h;
}
__device__ __forceinline__ float ftanh(float x) {
  const float ax = fabsf(x);
  const float e = __expf(-2.f * ax);
  const float t = __fdividef(1.f - e, 1.f + e);
  return copysignf(t, x);
}
__device__ __forceinline__ f32x4 mfma16(uint4 a, uint4 b, f32x4 c) {
  return __builtin_amdgcn_mfma_f32_16x16x32_bf16(
      __builtin_bit_cast(short8, a), __builtin_bit_cast(short8, b), c, 0, 0, 0);
}
// unpack 8 packed (lo<<16|hi) u32 -> hi-frag / lo-frag (round-4 proven)
__device__ __forceinline__ void unpack_pair(uint4 p0, uint4 p1,
                                            uint4& avh, uint4& avl) {
  avh.x = __builtin_amdgcn_perm(p0.y, p0.x, 0x05040100u);
  avh.y = __builtin_amdgcn_perm(p0.w, p0.z, 0x05040100u);
  avh.z = __builtin_amdgcn_perm(p1.y, p1.x, 0x05040100u);
  avh.w = __builtin_amdgcn_perm(p1.w, p1.z, 0x05040100u);
  avl.x = __builtin_amdgcn_perm(p0.y, p0.x, 0x07060302u);
  avl.y = __builtin_amdgcn_perm(p0.w, p0.z, 0x07060302u);
  avl.z = __builtin_amdgcn_perm(p1.y, p1.x, 0x07060302u);
  avl.w = __builtin_amdgcn_perm(p1.w, p1.z, 0x07060302u);
}

// ------------------------------- prep (fast) -------------------------------
__global__ void prep_pack(
    const float* __restrict__ eW0, const float* __restrict__ eH0,
    const float* __restrict__ eb_ih0, const float* __restrict__ eb_hh0,
    const float* __restrict__ eW1, const float* __restrict__ eH1,
    const float* __restrict__ eb_ih1, const float* __restrict__ eb_hh1,
    const float* __restrict__ dW0, const float* __restrict__ dH0,
    const float* __restrict__ db_ih0, const float* __restrict__ db_hh0,
    const float* __restrict__ dW1, const float* __restrict__ dH1,
    const float* __restrict__ db_ih1, const float* __restrict__ db_hh1,
    const float* __restrict__ linW, const float* __restrict__ linb,
    unsigned short* __restrict__ pk, float* __restrict__ bfin,
    int* __restrict__ cnt0) {
  const int e = blockIdx.x * 256 + threadIdx.x;
  if (e >= 513680) return;
  if (e >= 513168) { cnt0[e - 513168] = 0; return; }  // pipeline counters
  if (e < 262144) {  // recurrent U matrices (256x256)
    const int um = e >> 16, le = e & 65535;
    const int j = le & 7, lane = (le >> 3) & 63, tile = (le >> 9) & 15, kk = le >> 13;
    const int n = tile * 16 + (lane & 15), k = kk * 32 + ((lane >> 4) << 3) + j;
    const float* U = (um == 0) ? eH0 : (um == 1) ? eH1 : (um == 2) ? dH0 : dH1;
    const float x = U[n * 256 + k];
    const unsigned short h = f2bf(x);
    const int base = um * 131072;
    pk[base + le] = h;
    pk[base + 65536 + le] = f2bf(x - bf2f(h));
  } else if (e < 344064) {  // eW0 / dW0 (256x131, K pad 160, KK=5)
    const bool isD = (e >= 303104);
    const int e2 = e - (isD ? 303104 : 262144);
    const int j = e2 & 7, lane = (e2 >> 3) & 63, tile = (e2 >> 9) & 15, kk = e2 >> 13;
    const int n = tile * 16 + (lane & 15), k = kk * 32 + ((lane >> 4) << 3) + j;
    const float* W = isD ? dW0 : eW0;
    const float x = (k < IND) ? W[n * IND + k] : 0.f;
    const unsigned short h = f2bf(x);
    const int base = isD ? DW0 : EW0;
    pk[base + e2] = h;
    pk[base + 40960 + e2] = f2bf(x - bf2f(h));
  } else if (e < 475136) {  // eW1 / dW1 (256x256, KK=8)
    const bool isD = (e >= 409600);
    const int e2 = e - (isD ? 409600 : 344064);
    const int j = e2 & 7, lane = (e2 >> 3) & 63, tile = (e2 >> 9) & 15, kk = e2 >> 13;
    const int n = tile * 16 + (lane & 15), k = kk * 32 + ((lane >> 4) << 3) + j;
    const float* W = isD ? dW1 : eW1;
    const float x = W[n * 256 + k];
    const unsigned short h = f2bf(x);
    const int base = isD ? DW1 : EW1;
    pk[base + e2] = h;
    pk[base + 65536 + e2] = f2bf(x - bf2f(h));
  } else if (e < 512000) {  // lin_W (131x256 -> 144 cols pad, 9 tiles, KK=8)
    const int e2 = e - 475136;
    const int kk = e2 / 4608;
    const int rem = e2 - kk * 4608;
    const int t9 = rem >> 9, le = rem & 511;
    const int j = le & 7, lane = le >> 3;
    const int n = t9 * 16 + (lane & 15), k = kk * 32 + ((lane >> 4) << 3) + j;
    const float x = (n < OUTD) ? linW[n * 256 + k] : 0.f;
    const unsigned short h = f2bf(x);
    pk[LINP + e2] = h;
    pk[LINP + 36864 + e2] = f2bf(x - bf2f(h));
  } else {  // combined biases + padded lin bias
    const int e3 = e - 512000;
    if (e3 < 256) bfin[e3] = eb_ih0[e3] + eb_hh0[e3];
    else if (e3 < 512) { const int j = e3 - 256; bfin[e3] = eb_ih1[j] + eb_hh1[j]; }
    else if (e3 < 768) { const int j = e3 - 512; bfin[e3] = db_ih0[j] + db_hh0[j]; }
    else if (e3 < 1024){ const int j = e3 - 768; bfin[e3] = db_ih1[j] + db_hh1[j]; }
    else { const int j = e3 - 1024; bfin[e3] = (j < OUTD) ? linb[j] : -1e30f; }
  }
}

// ------------------------- batched input projection ------------------------
__global__ __launch_bounds__(256) void gemm_proj(
    const float* __restrict__ A, const float* __restrict__ X1023,
    const float* __restrict__ Yp, const int amode, const int K, const int KK,
    const unsigned short* __restrict__ Wh, const unsigned short* __restrict__ Wl,
    const float* __restrict__ bias, float* __restrict__ Pout) {
  __shared__ unsigned short Ah[64][40];
  __shared__ unsigned short Al[64][40];
  const int tid = threadIdx.x, lane = tid & 63, wid = tid >> 6;
  const int mbase = blockIdx.x * 64;
  const int cg = blockIdx.y;
  const int srow = tid >> 2, kidx = (tid & 3) << 3;
  const float* rowptr;
  {
    const int grow = mbase + srow;
    if (amode) {
      const int t = grow >> 8, b = grow & 255;
      rowptr = t ? (Yp + ((size_t)(t - 1) * 256 + b) * IND) : (X1023 + (size_t)b * IND);
    } else {
      rowptr = A + (size_t)grow * K;
    }
  }
  const f32x4 z = {0.f, 0.f, 0.f, 0.f};
  f32x4 acc[4] = {z, z, z, z};
  const uint4* Wh4 = (const uint4*)Wh;
  const uint4* Wl4 = (const uint4*)Wl;
  for (int kk = 0; kk < KK; ++kk) {
    const int k0 = kk << 5;
    __syncthreads();
    float v[8];
#pragma unroll
    for (int j = 0; j < 8; ++j) {
      const int kg = k0 + kidx + j;
      v[j] = (kg < K) ? rowptr[kg] : 0.f;
    }
#pragma unroll
    for (int j = 0; j < 8; ++j) {
      const unsigned short h = f2bf(v[j]);
      Ah[srow][kidx + j] = h;
      Al[srow][kidx + j] = f2bf(v[j] - bf2f(h));
    }
    __syncthreads();
    const uint4 avh = *(const uint4*)&Ah[(wid << 4) + (lane & 15)][(lane >> 4) << 3];
    const uint4 avl = *(const uint4*)&Al[(wid << 4) + (lane & 15)][(lane >> 4) << 3];
#pragma unroll
    for (int tt = 0; tt < 4; ++tt) {
      const int bi = ((kk << 4) + (cg << 2) + tt) * 64 + lane;
      const uint4 bh = Wh4[bi], bl = Wl4[bi];
      acc[tt] = mfma16(avh, bh, acc[tt]);
      acc[tt] = mfma16(avh, bl, acc[tt]);
      acc[tt] = mfma16(avl, bh, acc[tt]);
    }
  }
#pragma unroll
  for (int tt = 0; tt < 4; ++tt) {
    const int col = ((cg << 2) + tt) * 16 + (lane & 15);
    const float bcol = bias[col];
#pragma unroll
    for (int r = 0; r < 4; ++r) {
      const int row = mbase + (wid << 4) + ((lane >> 4) << 2) + r;
      Pout[(size_t)row * 256 + col] = acc[tt][r] + bcol;
    }
  }
}

// ---------------------------- 3-stage pipeline -----------------------------
// grid 48 x 512. role = bid/16. Per-group g: role0 rows [16g,16g+16).
__global__ __launch_bounds__(512, 2) void pipe_kernel(
    const float* __restrict__ Pin,            // role0 input projections (f32)
    unsigned* __restrict__ xring,             // role0 -> role1 (packed u32)
    unsigned* __restrict__ p1ring,            // role1 -> role2 (packed u32)
    int* __restrict__ cnt,                    // counters for this kernel
    const unsigned short* __restrict__ U0p,   // role0 recurrent weights
    const unsigned short* __restrict__ W1p,   // role1 projection weights
    const float* __restrict__ b1,             // role1 bias (combined)
    const unsigned short* __restrict__ U1p,   // role2 recurrent weights
    const float* __restrict__ h0init, const float* __restrict__ h1init,
    float* __restrict__ fin0out, float* __restrict__ fin1out,
    float* __restrict__ outBuf) {             // role2 per-step out (or null)
  __shared__ __align__(16) unsigned A2[2][16][260];
  const int tid = threadIdx.x, lane = tid & 63, wid = tid >> 6;
  const int bid = blockIdx.x;
  const int role = bid >> 4;
  const int g = bid & 15;
  const int r0g = g << 4;
  const int rowl = (lane >> 4) << 2;
  const int colb = (wid << 5) + (lane & 15);
  const f32x4 z = {0.f, 0.f, 0.f, 0.f};

  if (role == 1) {
    // ---------------- projection stage: p1_t = x_t @ W1^T + b1 -------------
    const uint4* W4 = (const uint4*)W1p;  // lo at +8192
    uint4 wf[2][2][8];
#pragma unroll
    for (int tt = 0; tt < 2; ++tt)
#pragma unroll
      for (int kk = 0; kk < 8; ++kk) {
        const int idx = ((kk << 4) + wid * 2 + tt) * 64 + lane;
        wf[0][tt][kk] = W4[idx];
        wf[1][tt][kk] = W4[idx + 8192];
      }
    const float btt0 = b1[colb], btt1 = b1[colb + 16];
    const unsigned* xr_g = xring + (size_t)g * RING * 4096;
    unsigned* pr_g = p1ring + (size_t)g * RING * 8 * 512;
    int* flagX = cnt + g;                  // role0 progress
    int* myflag = cnt + 32 + g * 8 + wid;  // this wave's output flag
    int* cons1p = cnt + 160 + g;           // role2 progress (backpressure)
    int cachedProd = 0, cachedCons = 0;
    for (int t = 0; t < TSTEPS; ++t) {
      if (cachedProd <= t) {  // wait for x tile t (wave-level, cached)
        int nv = 0;
        if (lane == 0) {
          int v = cachedProd, it = 0;
          while (v <= t && ++it < POLLCAP) v = atomicAdd(flagX, 0);
          nv = v;
        }
        cachedProd = __shfl(nv, 0);
        __threadfence();  // acquire: invalidate stale lines before tile read
      }
      if (t - cachedCons >= RING - 64) {  // ring backpressure
        int nv = 0;
        if (lane == 0) {
          int v = cachedCons, it = 0;
          while (t - v >= RING - 64 && ++it < POLLCAP) v = atomicAdd(cons1p, 0);
          nv = v;
        }
        cachedCons = __shfl(nv, 0);
      }
      const unsigned* xt = xr_g + (size_t)(t & (RING - 1)) * 4096;
      f32x4 hh[2] = {z, z}, hl[2] = {z, z}, lh[2] = {z, z};
#pragma unroll
      for (int kk = 0; kk < 8; ++kk) {
        const unsigned* base = xt + (lane & 15) * 256 + (kk << 5) + ((lane >> 4) << 3);
        const uint4 p0 = *(const uint4*)base;
        const uint4 p1v = *(const uint4*)(base + 4);
        uint4 avh, avl;
        unpack_pair(p0, p1v, avh, avl);
        hh[0] = mfma16(avh, wf[0][0][kk], hh[0]);
        hh[1] = mfma16(avh, wf[0][1][kk], hh[1]);
        hl[0] = mfma16(avh, wf[1][0][kk], hl[0]);
        hl[1] = mfma16(avh, wf[1][1][kk], hl[1]);
        lh[0] = mfma16(avl, wf[0][0][kk], lh[0]);
        lh[1] = mfma16(avl, wf[0][1][kk], lh[1]);
      }
      uint4 oa, ob;
      {
        unsigned o[8];
#pragma unroll
        for (int tt = 0; tt < 2; ++tt) {
          const float bb = tt ? btt1 : btt0;
#pragma unroll
          for (int r = 0; r < 4; ++r) {
            const float pv = (hh[tt][r] + hl[tt][r]) + lh[tt][r] + bb;
            o[tt * 4 + r] = packbf(pv);
          }
        }
        oa = make_uint4(o[0], o[1], o[2], o[3]);
        ob = make_uint4(o[4], o[5], o[6], o[7]);
      }
      unsigned* dst = pr_g + ((size_t)(t & (RING - 1)) * 8 + wid) * 512 + lane * 8;
      *(uint4*)dst = oa;
      *(uint4*)(dst + 4) = ob;
      __threadfence();  // release own stores
      if (lane == 0) atomicExch(myflag, t + 1);
      if ((t & 31) == 31) {  // loose block sync + xring-consumed bump
        __syncthreads();
        if (tid == 0) atomicExch(cnt + 16 + g, t + 1);
      }
    }
    return;
  }

  // ---------------- scan stages (role 0 and role 2) ------------------------
  const unsigned short* Up = (role == 0) ? U0p : U1p;
  const uint4* U4 = (const uint4*)Up;  // lo at +8192
  uint4 uf[2][2][8];
#pragma unroll
  for (int tt = 0; tt < 2; ++tt)
#pragma unroll
    for (int kk = 0; kk < 8; ++kk) {
      const int idx = ((kk << 4) + wid * 2 + tt) * 64 + lane;
      uf[0][tt][kk] = U4[idx];
      uf[1][tt][kk] = U4[idx + 8192];
    }
  {
    const float* hinit = (role == 0) ? h0init : h1init;
#pragma unroll
    for (int j = 0; j < 8; ++j) {
      const int e = tid * 8 + j;
      const int row = e >> 8, col = e & 255;
      const float x = hinit ? hinit[((r0g + row) << 8) + col] : 0.f;
      A2[0][row][col] = packbf(x);
    }
  }
  __syncthreads();
  float* fbase;
  {
    float* ft = (role == 0) ? fin0out : fin1out;
    fbase = ft ? (ft + ((size_t)(r0g + rowl) << 8) + colb) : (float*)0;
  }

  if (role == 0) {
    // ---- L0 scan: reads Pin (f32, prefetched), publishes xring tiles ------
    const float* pin_base = Pin + ((size_t)(r0g + rowl) << 8) + colb;
    unsigned* xr_g = xring + (size_t)g * RING * 4096;
    int* flag = cnt + g;
    int* consp = cnt + 16 + g;
    int cachedCons = 0;
    float pc[2][4];
#pragma unroll
    for (int tt = 0; tt < 2; ++tt)
#pragma unroll
      for (int r = 0; r < 4; ++r) pc[tt][r] = pin_base[tt * 16 + r * 256];
    for (int t = 0; t < TSTEPS; ++t) {
      const int cur = t & 1, nxt = cur ^ 1;
      if (t - cachedCons >= RING - 64) {  // backpressure vs role1
        int nv = 0;
        if (lane == 0) {
          int v = cachedCons, it = 0;
          while (t - v >= RING - 64 && ++it < POLLCAP) v = atomicAdd(consp, 0);
          nv = v;
        }
        cachedCons = __shfl(nv, 0);
      }
      float pn[2][4];
      {
        const int tn = (t + 1 < TSTEPS) ? (t + 1) : t;
        const float* ptn = pin_base + (size_t)tn * 65536;
#pragma unroll
        for (int tt = 0; tt < 2; ++tt)
#pragma unroll
          for (int r = 0; r < 4; ++r) pn[tt][r] = ptn[tt * 16 + r * 256];
      }
      f32x4 hh[2] = {z, z}, hl[2] = {z, z}, lh[2] = {z, z};
#pragma unroll
      for (int kk = 0; kk < 8; ++kk) {
        const int koff = (kk << 5) + ((lane >> 4) << 3);
        const uint4 p0 = *(const uint4*)&A2[cur][lane & 15][koff];
        const uint4 p1v = *(const uint4*)&A2[cur][lane & 15][koff + 4];
        uint4 avh, avl;
        unpack_pair(p0, p1v, avh, avl);
        hh[0] = mfma16(avh, uf[0][0][kk], hh[0]);
        hh[1] = mfma16(avh, uf[0][1][kk], hh[1]);
        hl[0] = mfma16(avh, uf[1][0][kk], hl[0]);
        hl[1] = mfma16(avh, uf[1][1][kk], hl[1]);
        lh[0] = mfma16(avl, uf[0][0][kk], lh[0]);
        lh[1] = mfma16(avl, uf[0][1][kk], lh[1]);
      }
      unsigned* xt = xr_g + (size_t)(t & (RING - 1)) * 4096;
#pragma unroll
      for (int tt = 0; tt < 2; ++tt) {
#pragma unroll
        for (int r = 0; r < 4; ++r) {
          const float av = (hh[tt][r] + hl[tt][r]) + lh[tt][r];
          const float x = ftanh(av + pc[tt][r]);
          const unsigned u = packbf(x);
          A2[nxt][rowl + r][colb + tt * 16] = u;
          xt[(rowl + r) * 256 + colb + tt * 16] = u;
          if (fbase && t == TSTEPS - 1) fbase[tt * 16 + r * 256] = x;
        }
      }
      // release: all threads' xring stores visible, then publish tile t.
      __threadfence();   // drains vm/lgkm + L2 writeback (also LDS exchange)
      __syncthreads();
      if (tid == 0) atomicExch(flag, t + 1);
#pragma unroll
      for (int tt = 0; tt < 2; ++tt)
#pragma unroll
        for (int r = 0; r < 4; ++r) pc[tt][r] = pn[tt][r];
    }
  } else {
    // ---- L1 scan: consumes p1ring (per-wave flags), optional out ----------
    const unsigned* pr_g = p1ring + (size_t)g * RING * 8 * 512;
    int* myflag = cnt + 32 + g * 8 + wid;
    float* outb = outBuf ? (outBuf + ((size_t)(r0g + rowl) << 8) + colb) : (float*)0;
    int cachedProd = 0;
    for (int t = 0; t < TSTEPS; ++t) {
      const int cur = t & 1, nxt = cur ^ 1;
      if (cachedProd <= t) {
        int nv = 0;
        if (lane == 0) {
          int v = cachedProd, it = 0;
          while (v <= t && ++it < POLLCAP) v = atomicAdd(myflag, 0);
          nv = v;
        }
        cachedProd = __shfl(nv, 0);
        __threadfence();  // acquire
      }
      const unsigned* src = pr_g + ((size_t)(t & (RING - 1)) * 8 + wid) * 512 + lane * 8;
      const uint4 pa = *(const uint4*)src;
      const uint4 pb = *(const uint4*)(src + 4);
      f32x4 hh[2] = {z, z}, hl[2] = {z, z}, lh[2] = {z, z};
#pragma unroll
      for (int kk = 0; kk < 8; ++kk) {
        const int koff = (kk << 5) + ((lane >> 4) << 3);
        const uint4 p0 = *(const uint4*)&A2[cur][lane & 15][koff];
        const uint4 p1v = *(const uint4*)&A2[cur][lane & 15][koff + 4];
        uint4 avh, avl;
        unpack_pair(p0, p1v, avh, avl);
        hh[0] = mfma16(avh, uf[0][0][kk], hh[0]);
        hh[1] = mfma16(avh, uf[0][1][kk], hh[1]);
        hl[0] = mfma16(avh, uf[1][0][kk], hl[0]);
        hl[1] = mfma16(avh, uf[1][1][kk], hl[1]);
        lh[0] = mfma16(avl, uf[0][0][kk], lh[0]);
        lh[1] = mfma16(avl, uf[0][1][kk], lh[1]);
      }
      float* pot = outb ? (outb + (size_t)t * 65536) : (float*)0;
#pragma unroll
      for (int tt = 0; tt < 2; ++tt) {
#pragma unroll
        for (int r = 0; r < 4; ++r) {
          const unsigned pu = tt ? ((r == 0) ? pb.x : (r == 1) ? pb.y : (r == 2) ? pb.z : pb.w)
                                 : ((r == 0) ? pa.x : (r == 1) ? pa.y : (r == 2) ? pa.z : pa.w);
          const float p = bf2f((unsigned short)(pu & 0xffffu)) +
                          bf2f((unsigned short)(pu >> 16));
          const float av = (hh[tt][r] + hl[tt][r]) + lh[tt][r];
          const float x = ftanh(av + p);
          A2[nxt][rowl + r][colb + tt * 16] = packbf(x);
          if (pot) pot[tt * 16 + r * 256] = x;
          if (fbase && t == TSTEPS - 1) fbase[tt * 16 + r * 256] = x;
        }
      }
      // cheap LDS-exchange barrier (out stores may stay in flight)
      asm volatile("s_waitcnt lgkmcnt(0)\n\ts_barrier" ::: "memory");
      if ((t & 31) == 31 && tid == 0) atomicExch(cnt + 160 + g, t + 1);
    }
  }
}

// ------------------------------ head + softmax -----------------------------
__global__ __launch_bounds__(256) void head_kernel(
    const float* __restrict__ A, const unsigned short* __restrict__ Wh,
    const unsigned short* __restrict__ Wl, const float* __restrict__ biasp,
    float* __restrict__ out) {
  __shared__ unsigned short Ah[64][40];
  __shared__ unsigned short Al[64][40];
  const int tid = threadIdx.x, lane = tid & 63, wid = tid >> 6;
  const int mbase = blockIdx.x * 64;
  const int srow = tid >> 2, kidx = (tid & 3) << 3;
  const float* rowptr = A + (size_t)(mbase + srow) * 256;
  const f32x4 z = {0.f, 0.f, 0.f, 0.f};
  f32x4 acc[9] = {z, z, z, z, z, z, z, z, z};
  const uint4* Wh4 = (const uint4*)Wh;
  const uint4* Wl4 = (const uint4*)Wl;
  for (int kk = 0; kk < 8; ++kk) {
    const int k0 = kk << 5;
    __syncthreads();
#pragma unroll
    for (int j = 0; j < 8; ++j) {
      const float v = rowptr[k0 + kidx + j];
      const unsigned short h = f2bf(v);
      Ah[srow][kidx + j] = h;
      Al[srow][kidx + j] = f2bf(v - bf2f(h));
    }
    __syncthreads();
    const uint4 avh = *(const uint4*)&Ah[(wid << 4) + (lane & 15)][(lane >> 4) << 3];
    const uint4 avl = *(const uint4*)&Al[(wid << 4) + (lane & 15)][(lane >> 4) << 3];
#pragma unroll
    for (int tt = 0; tt < 9; ++tt) {
      const int bi = (kk * 9 + tt) * 64 + lane;
      const uint4 bh = Wh4[bi], bl = Wl4[bi];
      acc[tt] = mfma16(avh, bh, acc[tt]);
      acc[tt] = mfma16(avh, bl, acc[tt]);
      acc[tt] = mfma16(avl, bh, acc[tt]);
    }
  }
#pragma unroll
  for (int tt = 0; tt < 9; ++tt) {
    const float b = biasp[tt * 16 + (lane & 15)];
#pragma unroll
    for (int r = 0; r < 4; ++r) acc[tt][r] += b;
  }
  float lse[4];
#pragma unroll
  for (int r = 0; r < 4; ++r) {
    float m = acc[0][r];
#pragma unroll
    for (int tt = 1; tt < 9; ++tt) m = fmaxf(m, acc[tt][r]);
    m = fmaxf(m, __shfl_xor(m, 1));
    m = fmaxf(m, __shfl_xor(m, 2));
    m = fmaxf(m, __shfl_xor(m, 4));
    m = fmaxf(m, __shfl_xor(m, 8));
    float s = 0.f;
#pragma unroll
    for (int tt = 0; tt < 9; ++tt) s += __expf(acc[tt][r] - m);
    s += __shfl_xor(s, 1);
    s += __shfl_xor(s, 2);
    s += __shfl_xor(s, 4);
    s += __shfl_xor(s, 8);
    lse[r] = m + __logf(s);
  }
#pragma unroll
  for (int tt = 0; tt < 9; ++tt) {
    const int col = tt * 16 + (lane & 15);
    if (col < OUTD) {
#pragma unroll
      for (int r = 0; r < 4; ++r) {
        const int row = mbase + (wid << 4) + ((lane >> 4) << 2) + r;
        out[(size_t)row * OUTD + col] = acc[tt][r] - lse[r];
      }
    }
  }
}

// ========================= slow fallback (round 1) =========================
__device__ __forceinline__ void packWs(float* __restrict__ ws, const float* __restrict__ src,
                                       int e, int off, int K, int ncols) {
  const int le = e - off;
  const int m = le & 3;
  const int tt = le >> 2;
  const int j = tt % ncols;
  const int k4 = tt / ncols;
  const int k = k4 * 4 + m;
  ws[e] = (k < K) ? src[j * K + k] : 0.f;
}

__global__ void prep_slow(
    const float* __restrict__ eW0, const float* __restrict__ eH0,
    const float* __restrict__ eb_ih0, const float* __restrict__ eb_hh0,
    const float* __restrict__ eW1, const float* __restrict__ eH1,
    const float* __restrict__ eb_ih1, const float* __restrict__ eb_hh1,
    const float* __restrict__ dW0, const float* __restrict__ dH0,
    const float* __restrict__ db_ih0, const float* __restrict__ db_hh0,
    const float* __restrict__ dW1, const float* __restrict__ dH1,
    const float* __restrict__ db_ih1, const float* __restrict__ db_hh1,
    const float* __restrict__ linW, float* __restrict__ ws) {
  const int e = blockIdx.x * 256 + threadIdx.x;
  if (e >= WS_TOTAL_SLOW) return;
  if (e < OFF_EH0s)      packWs(ws, eW0, e, OFF_EW0s, IND, 256);
  else if (e < OFF_EW1s) packWs(ws, eH0, e, OFF_EH0s, 256, 256);
  else if (e < OFF_EH1s) packWs(ws, eW1, e, OFF_EW1s, 256, 256);
  else if (e < OFF_DW0s) packWs(ws, eH1, e, OFF_EH1s, 256, 256);
  else if (e < OFF_DH0s) packWs(ws, dW0, e, OFF_DW0s, IND, 256);
  else if (e < OFF_DW1s) packWs(ws, dH0, e, OFF_DH0s, 256, 256);
  else if (e < OFF_DH1s) packWs(ws, dW1, e, OFF_DW1s, 256, 256);
  else if (e < OFF_LWs)  packWs(ws, dH1, e, OFF_DH1s, 256, 256);
  else if (e < OFF_EB0s) packWs(ws, linW, e, OFF_LWs, 256, OUTD);
  else if (e < OFF_EB1s) { int j = e - OFF_EB0s; ws[e] = eb_ih0[j] + eb_hh0[j]; }
  else if (e < OFF_DB0s) { int j = e - OFF_EB1s; ws[e] = eb_ih1[j] + eb_hh1[j]; }
  else if (e < OFF_DB1s) { int j = e - OFF_DB0s; ws[e] = db_ih0[j] + db_hh0[j]; }
  else                   { int j = e - OFF_DB1s; ws[e] = db_ih1[j] + db_hh1[j]; }
}

__device__ __forceinline__ float dot4(const float4 a, const float4 b, float acc) {
  acc = fmaf(a.x, b.x, acc);
  acc = fmaf(a.y, b.y, acc);
  acc = fmaf(a.z, b.z, acc);
  acc = fmaf(a.w, b.w, acc);
  return acc;
}

__device__ __forceinline__ float2 layer_in(
    const float4* __restrict__ wih, const float4* __restrict__ whh,
    const float* __restrict__ x0, const float* __restrict__ x1,
    const float* __restrict__ h0, const float* __restrict__ h1,
    const float bias, const int tid) {
  float a0 = bias, a1 = bias;
#pragma unroll 4
  for (int k4 = 0; k4 < 33; ++k4) {
    const float4 w = wih[k4 * 256 + tid];
    a0 = dot4(*(const float4*)(x0 + k4 * 4), w, a0);
    a1 = dot4(*(const float4*)(x1 + k4 * 4), w, a1);
  }
#pragma unroll 4
  for (int k4 = 0; k4 < 64; ++k4) {
    const float4 w = whh[k4 * 256 + tid];
    a0 = dot4(*(const float4*)(h0 + k4 * 4), w, a0);
    a1 = dot4(*(const float4*)(h1 + k4 * 4), w, a1);
  }
  return make_float2(a0, a1);
}

__device__ __forceinline__ float2 layer_hh(
    const float4* __restrict__ wih, const float4* __restrict__ whh,
    const float* __restrict__ x0, const float* __restrict__ x1,
    const float* __restrict__ h0, const float* __restrict__ h1,
    const float bias, const int tid) {
  float a0 = bias, a1 = bias;
#pragma unroll 4
  for (int k4 = 0; k4 < 64; ++k4) {
    const float4 wi = wih[k4 * 256 + tid];
    const float4 wh = whh[k4 * 256 + tid];
    a0 = dot4(*(const float4*)(x0 + k4 * 4), wi, a0);
    a1 = dot4(*(const float4*)(x1 + k4 * 4), wi, a1);
    a0 = dot4(*(const float4*)(h0 + k4 * 4), wh, a0);
    a1 = dot4(*(const float4*)(h1 + k4 * 4), wh, a1);
  }
  return make_float2(a0, a1);
}

__global__ __launch_bounds__(256, 1) void rnn_slow(
    const float* __restrict__ X, const float* __restrict__ Y,
    const float* __restrict__ ws, const float* __restrict__ linb,
    float* __restrict__ out) {
  __shared__ __align__(16) float xb[2][132];
  __shared__ __align__(16) float h0s[2][256];
  __shared__ __align__(16) float h1s[2][256];
  __shared__ __align__(16) float lo[2][132];
  const int tid = threadIdx.x;
  const int r0 = blockIdx.x * 2;
  const float4* ew0 = (const float4*)(ws + OFF_EW0s);
  const float4* eh0 = (const float4*)(ws + OFF_EH0s);
  const float4* ew1 = (const float4*)(ws + OFF_EW1s);
  const float4* eh1 = (const float4*)(ws + OFF_EH1s);
  const float4* dw0 = (const float4*)(ws + OFF_DW0s);
  const float4* dh0 = (const float4*)(ws + OFF_DH0s);
  const float4* dw1 = (const float4*)(ws + OFF_DW1s);
  const float4* dh1 = (const float4*)(ws + OFF_DH1s);
  const float4* lw  = (const float4*)(ws + OFF_LWs);
  const float eb0v = ws[OFF_EB0s + tid];
  const float eb1v = ws[OFF_EB1s + tid];
  const float db0v = ws[OFF_DB0s + tid];
  const float db1v = ws[OFF_DB1s + tid];
  h0s[0][tid] = 0.f; h0s[1][tid] = 0.f;
  h1s[0][tid] = 0.f; h1s[1][tid] = 0.f;
  __syncthreads();
  for (int t = 0; t < TSTEPS; ++t) {
    {
      const int r = tid / 132, i = tid - r * 132;
      xb[r][i] = (i < IND) ? X[((size_t)t * BATCH + r0 + r) * IND + i] : 0.f;
      if (tid < 8) {
        const int i2 = tid + 124;
        xb[1][i2] = (i2 < IND) ? X[((size_t)t * BATCH + r0 + 1) * IND + i2] : 0.f;
      }
    }
    __syncthreads();
    const float2 a = layer_in(ew0, eh0, xb[0], xb[1], h0s[0], h0s[1], eb0v, tid);
    const float n0a = ftanh(a.x), n0b = ftanh(a.y);
    __syncthreads();
    h0s[0][tid] = n0a; h0s[1][tid] = n0b;
    __syncthreads();
    const float2 b = layer_hh(ew1, eh1, h0s[0], h0s[1], h1s[0], h1s[1], eb1v, tid);
    const float n1a = ftanh(b.x), n1b = ftanh(b.y);
    __syncthreads();
    h1s[0][tid] = n1a; h1s[1][tid] = n1b;
    __syncthreads();
  }
  for (int t = 0; t < TSTEPS; ++t) {
    const float* xbase = (t == 0) ? (X + (size_t)TSTEPS * BATCH * IND)
                                  : (Y + (size_t)(t - 1) * BATCH * IND);
    {
      const int r = tid / 132, i = tid - r * 132;
      xb[r][i] = (i < IND) ? xbase[(size_t)(r0 + r) * IND + i] : 0.f;
      if (tid < 8) {
        const int i2 = tid + 124;
        xb[1][i2] = (i2 < IND) ? xbase[(size_t)(r0 + 1) * IND + i2] : 0.f;
      }
    }
    __syncthreads();
    const float2 a = layer_in(dw0, dh0, xb[0], xb[1], h0s[0], h0s[1], db0v, tid);
    const float n0a = ftanh(a.x), n0b = ftanh(a.y);
    __syncthreads();
    h0s[0][tid] = n0a; h0s[1][tid] = n0b;
    __syncthreads();
    const float2 b = layer_hh(dw1, dh1, h0s[0], h0s[1], h1s[0], h1s[1], db1v, tid);
    const float n1a = ftanh(b.x), n1b = ftanh(b.y);
    __syncthreads();
    h1s[0][tid] = n1a; h1s[1][tid] = n1b;
    __syncthreads();
    if (tid < OUTD) {
      float c0 = linb[tid], c1 = linb[tid];
#pragma unroll 4
      for (int k4 = 0; k4 < 64; ++k4) {
        const float4 w = lw[k4 * OUTD + tid];
        c0 = dot4(*(const float4*)&h1s[0][k4 * 4], w, c0);
        c1 = dot4(*(const float4*)&h1s[1][k4 * 4], w, c1);
      }
      lo[0][tid] = c0;
      lo[1][tid] = c1;
    }
    __syncthreads();
    const int wid = tid >> 6, lane = tid & 63;
    if (wid < 2) {
      float m = -3.0e38f;
      for (int o = lane; o < OUTD; o += 64) m = fmaxf(m, lo[wid][o]);
#pragma unroll
      for (int off = 32; off > 0; off >>= 1) m = fmaxf(m, __shfl_xor(m, off, 64));
      float s = 0.f;
      for (int o = lane; o < OUTD; o += 64) s += __expf(lo[wid][o] - m);
#pragma unroll
      for (int off = 32; off > 0; off >>= 1) s += __shfl_xor(s, off, 64);
      const float lse = m + __logf(s);
      float* op = out + ((size_t)t * BATCH + r0 + wid) * OUTD;
      for (int o = lane; o < OUTD; o += 64) op[o] = lo[wid][o] - lse;
    }
    __syncthreads();
  }
}

// ================================ launcher =================================
extern "C" void kernel_launch(void* const* d_in, const int* in_sizes, int n_in,
                              void* d_out, int out_size, void* d_ws, size_t ws_size,
                              hipStream_t stream) {
  const float* X      = (const float*)d_in[0];
  const float* Y      = (const float*)d_in[1];
  const float* eW0    = (const float*)d_in[2];
  const float* eH0    = (const float*)d_in[3];
  const float* eb_ih0 = (const float*)d_in[4];
  const float* eb_hh0 = (const float*)d_in[5];
  const float* eW1    = (const float*)d_in[6];
  const float* eH1    = (const float*)d_in[7];
  const float* eb_ih1 = (const float*)d_in[8];
  const float* eb_hh1 = (const float*)d_in[9];
  const float* dW0    = (const float*)d_in[10];
  const float* dH0    = (const float*)d_in[11];
  const float* db_ih0 = (const float*)d_in[12];
  const float* db_hh0 = (const float*)d_in[13];
  const float* dW1    = (const float*)d_in[14];
  const float* dH1    = (const float*)d_in[15];
  const float* db_ih1 = (const float*)d_in[16];
  const float* db_hh1 = (const float*)d_in[17];
  const float* linW   = (const float*)d_in[18];
  const float* linb   = (const float*)d_in[19];
  float* out = (float*)d_out;

  if (ws_size >= TOTAL_WS) {
    float* buf0 = (float*)d_ws;                       // P buffers / D1 out
    unsigned* ring = (unsigned*)((char*)d_ws + SB);   // buf1: rings + counters
    unsigned* xring = ring;                           // 64 MB
    unsigned* p1ring = ring + (size_t)16 * RING * 4096;  // 64 MB
    int* cnt_e = (int*)((char*)d_ws + 2 * SB - 4096); // counters at buf1 tail
    int* cnt_d = cnt_e + 256;
    unsigned short* pk = (unsigned short*)((char*)d_ws + PKB);
    float* bfin = (float*)((char*)d_ws + BFB);
    float* be0 = bfin, *be1 = bfin + 256, *bd0 = bfin + 512, *bd1 = bfin + 768;
    float* blin = bfin + 1024;
    float* fin0 = bfin + FIN0;
    float* fin1 = bfin + FIN1;
    const float* X1023 = X + (size_t)TSTEPS * BATCH * IND;

    prep_pack<<<2007, 256, 0, stream>>>(eW0, eH0, eb_ih0, eb_hh0, eW1, eH1, eb_ih1,
                                        eb_hh1, dW0, dH0, db_ih0, db_hh0, dW1, dH1,
                                        db_ih1, db_hh1, linW, linb, pk, bfin, cnt_e);
    // encoder: P_e0 -> buf0; pipelined L0 -> proj(W_e1) -> L1 (finals only)
    gemm_proj<<<dim3(MTOT / 64, 4), 256, 0, stream>>>(
        X, nullptr, nullptr, 0, IND, 5, pk + EW0, pk + EW0 + 40960, be0, buf0);
    pipe_kernel<<<48, 512, 0, stream>>>(
        buf0, xring, p1ring, cnt_e, pk + UE0, pk + EW1, be1, pk + UE1,
        nullptr, nullptr, fin0, fin1, nullptr);
    // decoder: P_d0 -> buf0; pipelined D0 -> proj(W_d1) -> D1 (out in-place)
    gemm_proj<<<dim3(MTOT / 64, 4), 256, 0, stream>>>(
        nullptr, X1023, Y, 1, IND, 5, pk + DW0, pk + DW0 + 40960, bd0, buf0);
    pipe_kernel<<<48, 512, 0, stream>>>(
        buf0, xring, p1ring, cnt_d, pk + UD0, pk + DW1, bd1, pk + UD1,
        fin0, fin1, nullptr, nullptr, buf0);
    // linear head + log_softmax
    head_kernel<<<MTOT / 64, 256, 0, stream>>>(buf0, pk + LINP, pk + LINP + 36864,
                                               blin, out);
  } else {
    float* ws = (float*)d_ws;
    prep_slow<<<(WS_TOTAL_SLOW + 255) / 256, 256, 0, stream>>>(
        eW0, eH0, eb_ih0, eb_hh0, eW1, eH1, eb_ih1, eb_hh1,
        dW0, dH0, db_ih0, db_hh0, dW1, dH1, db_ih1, db_hh1, linW, ws);
    rnn_slow<<<128, 256, 0, stream>>>(X, Y, ws, linb, out);
  }
}

// Round 10
// 8134.512 us; speedup vs baseline: 2.7701x; 2.7701x over previous
//
#include <hip/hip_runtime.h>
#include <cstddef>

// ---------------------------------------------------------------------------
// RNN_Reverser round 7 (3rd resubmit — rounds 7, 8, 9 all hit GPU-acquisition
// timeouts, no data): revert to sequential barrier-scan (round-5 pipeline
// post-mortem: cross-block per-step handoff = ~25,700 cy/step, 6x worse than
// a barrier step — __threadfence per step re-introduces the vmcnt drain +
// cross-XCD flag atomics on the critical path). Two changes on round-2 base:
//   1. Dependency-graph merge: e0 -> {e1, d0} -> d1. scan-e1 and scan-d0 are
//      independent; run them as ONE 32-block dispatch (two non-interacting
//      block groups, zero cross-block sync). 4 scans -> 3 scan-phases.
//   2. Packed-u32 h state (lo<<16|hi, proven correct in round 4) at the
//      proven 8-wave/512-thread shape: writes 8x ds_write_b32/thread (2-way
//      free banks) instead of 16x b16; reads 2x b128/kk + v_perm unpack.
// Buffers (in-place scans, round-0-proven pattern):
//   gemm-e0: X->buf0 | scan-e0: buf0 in-place, fin0 | gemm-e1: buf0->buf1
//   gemm-d0: X,Y->buf0 | scan2: [A] e1 on buf1 (fin1 only) ++ [B] d0 on buf0
//   in-place (init fin0) | gemm-d1: buf0->buf1 | scan-d1: buf1 in-place
//   (init fin1) | head: buf1 -> out.
// All matmuls split-bf16 (hh+hl+lh) for fp32-like precision.
// ---------------------------------------------------------------------------

typedef __attribute__((ext_vector_type(8))) short short8;
typedef __attribute__((ext_vector_type(4))) float f32x4;

namespace {
constexpr int TSTEPS = 1023;
constexpr int BATCH = 256;
constexpr int IND = 131;
constexpr int OUTD = 131;
constexpr int MTOT = TSTEPS * BATCH;  // 261888

// fast path ws layout (bytes)
constexpr size_t SB = (size_t)MTOT * 256 * 4;  // 268,173,312 one P buffer
// pack region: ushort offsets
constexpr int UE0 = 0;        // each U pack: hi 65536 + lo 65536
constexpr int UE1 = 131072;
constexpr int UD0 = 262144;
constexpr int UD1 = 393216;
constexpr int EW0 = 524288;   // proj K=131: hi 40960 + lo 40960
constexpr int DW0 = 606208;
constexpr int EW1 = 688128;   // proj K=256: hi 65536 + lo 65536
constexpr int DW1 = 819200;
constexpr int LINP = 950272;  // lin: hi 36864 + lo 36864
constexpr int PK_USH = 1024000;
constexpr size_t PKB = 2 * SB;                   // pack base (bytes)
constexpr size_t BFB = PKB + 2 * (size_t)PK_USH; // bias/finals float region
constexpr int FIN0 = 1168;
constexpr int FIN1 = 1168 + 65536;
constexpr size_t TOTAL_WS = BFB + (size_t)(1168 + 2 * 65536) * 4;  // 538,923,584

// slow path (round 1) float offsets
constexpr int OFF_EW0s = 0, OFF_EH0s = 33792, OFF_EW1s = 99328, OFF_EH1s = 164864;
constexpr int OFF_DW0s = 230400, OFF_DH0s = 264192, OFF_DW1s = 329728, OFF_DH1s = 395264;
constexpr int OFF_LWs = 460800, OFF_EB0s = 494336, OFF_EB1s = 494592;
constexpr int OFF_DB0s = 494848, OFF_DB1s = 495104;
constexpr int WS_TOTAL_SLOW = 495360;
}  // namespace

__device__ __forceinline__ unsigned short f2bf(float x) {
  unsigned u = __float_as_uint(x);
  u += 0x7fffu + ((u >> 16) & 1u);
  return (unsigned short)(u >> 16);
}
__device__ __forceinline__ float bf2f(unsigned short h) {
  return __uint_as_float(((unsigned)h) << 16);
}
__device__ __forceinline__ unsigned packbf(float x) {
  const unsigned short h = f2bf(x);
  const unsigned short l = f2bf(x - bf2f(h));
  return ((unsigned)l << 16) | (unsigned)h;
}
__device__ __forceinline__ float ftanh(float x) {
  const float ax = fabsf(x);
  const float e = __expf(-2.f * ax);
  const float t = __fdividef(1.f - e, 1.f + e);
  return copysignf(t, x);
}
__device__ __forceinline__ f32x4 mfma16(uint4 a, uint4 b, f32x4 c) {
  return __builtin_amdgcn_mfma_f32_16x16x32_bf16(
      __builtin_bit_cast(short8, a), __builtin_bit_cast(short8, b), c, 0, 0, 0);
}
// unpack 8 packed (lo<<16|hi) u32 -> hi-frag / lo-frag (round-4 proven)
__device__ __forceinline__ void unpack_pair(uint4 p0, uint4 p1,
                                            uint4& avh, uint4& avl) {
  avh.x = __builtin_amdgcn_perm(p0.y, p0.x, 0x05040100u);
  avh.y = __builtin_amdgcn_perm(p0.w, p0.z, 0x05040100u);
  avh.z = __builtin_amdgcn_perm(p1.y, p1.x, 0x05040100u);
  avh.w = __builtin_amdgcn_perm(p1.w, p1.z, 0x05040100u);
  avl.x = __builtin_amdgcn_perm(p0.y, p0.x, 0x07060302u);
  avl.y = __builtin_amdgcn_perm(p0.w, p0.z, 0x07060302u);
  avl.z = __builtin_amdgcn_perm(p1.y, p1.x, 0x07060302u);
  avl.w = __builtin_amdgcn_perm(p1.w, p1.z, 0x07060302u);
}

// ------------------------------- prep (fast) -------------------------------
// Packs all weights as hi/lo bf16 in MFMA B-fragment order:
//   frag element (kk, tile, lane, j) <- W[tile*16 + (lane&15)][kk*32 + (lane>>4)*8 + j]
__global__ void prep_pack(
    const float* __restrict__ eW0, const float* __restrict__ eH0,
    const float* __restrict__ eb_ih0, const float* __restrict__ eb_hh0,
    const float* __restrict__ eW1, const float* __restrict__ eH1,
    const float* __restrict__ eb_ih1, const float* __restrict__ eb_hh1,
    const float* __restrict__ dW0, const float* __restrict__ dH0,
    const float* __restrict__ db_ih0, const float* __restrict__ db_hh0,
    const float* __restrict__ dW1, const float* __restrict__ dH1,
    const float* __restrict__ db_ih1, const float* __restrict__ db_hh1,
    const float* __restrict__ linW, const float* __restrict__ linb,
    unsigned short* __restrict__ pk, float* __restrict__ bfin) {
  const int e = blockIdx.x * 256 + threadIdx.x;
  if (e >= 513168) return;
  if (e < 262144) {  // recurrent U matrices (256x256)
    const int um = e >> 16, le = e & 65535;
    const int j = le & 7, lane = (le >> 3) & 63, tile = (le >> 9) & 15, kk = le >> 13;
    const int n = tile * 16 + (lane & 15), k = kk * 32 + ((lane >> 4) << 3) + j;
    const float* U = (um == 0) ? eH0 : (um == 1) ? eH1 : (um == 2) ? dH0 : dH1;
    const float x = U[n * 256 + k];
    const unsigned short h = f2bf(x);
    const int base = um * 131072;
    pk[base + le] = h;
    pk[base + 65536 + le] = f2bf(x - bf2f(h));
  } else if (e < 344064) {  // eW0 / dW0 (256x131, K pad 160, KK=5)
    const bool isD = (e >= 303104);
    const int e2 = e - (isD ? 303104 : 262144);
    const int j = e2 & 7, lane = (e2 >> 3) & 63, tile = (e2 >> 9) & 15, kk = e2 >> 13;
    const int n = tile * 16 + (lane & 15), k = kk * 32 + ((lane >> 4) << 3) + j;
    const float* W = isD ? dW0 : eW0;
    const float x = (k < IND) ? W[n * IND + k] : 0.f;
    const unsigned short h = f2bf(x);
    const int base = isD ? DW0 : EW0;
    pk[base + e2] = h;
    pk[base + 40960 + e2] = f2bf(x - bf2f(h));
  } else if (e < 475136) {  // eW1 / dW1 (256x256, KK=8)
    const bool isD = (e >= 409600);
    const int e2 = e - (isD ? 409600 : 344064);
    const int j = e2 & 7, lane = (e2 >> 3) & 63, tile = (e2 >> 9) & 15, kk = e2 >> 13;
    const int n = tile * 16 + (lane & 15), k = kk * 32 + ((lane >> 4) << 3) + j;
    const float* W = isD ? dW1 : eW1;
    const float x = W[n * 256 + k];
    const unsigned short h = f2bf(x);
    const int base = isD ? DW1 : EW1;
    pk[base + e2] = h;
    pk[base + 65536 + e2] = f2bf(x - bf2f(h));
  } else if (e < 512000) {  // lin_W (131x256 -> 144 cols pad, 9 tiles, KK=8)
    const int e2 = e - 475136;
    const int kk = e2 / 4608;
    const int rem = e2 - kk * 4608;
    const int t9 = rem >> 9, le = rem & 511;
    const int j = le & 7, lane = le >> 3;
    const int n = t9 * 16 + (lane & 15), k = kk * 32 + ((lane >> 4) << 3) + j;
    const float x = (n < OUTD) ? linW[n * 256 + k] : 0.f;
    const unsigned short h = f2bf(x);
    pk[LINP + e2] = h;
    pk[LINP + 36864 + e2] = f2bf(x - bf2f(h));
  } else {  // combined biases + padded lin bias
    const int e3 = e - 512000;
    if (e3 < 256) bfin[e3] = eb_ih0[e3] + eb_hh0[e3];
    else if (e3 < 512) { const int j = e3 - 256; bfin[e3] = eb_ih1[j] + eb_hh1[j]; }
    else if (e3 < 768) { const int j = e3 - 512; bfin[e3] = db_ih0[j] + db_hh0[j]; }
    else if (e3 < 1024){ const int j = e3 - 768; bfin[e3] = db_ih1[j] + db_hh1[j]; }
    else { const int j = e3 - 1024; bfin[e3] = (j < OUTD) ? linb[j] : -1e30f; }
  }
}

// ------------------------- batched input projection ------------------------
// P[m][0..255] = A[m][0..K) @ W^T + bias ; grid (MTOT/64, 4), block 256.
__global__ __launch_bounds__(256) void gemm_proj(
    const float* __restrict__ A, const float* __restrict__ X1023,
    const float* __restrict__ Yp, const int amode, const int K, const int KK,
    const unsigned short* __restrict__ Wh, const unsigned short* __restrict__ Wl,
    const float* __restrict__ bias, float* __restrict__ Pout) {
  __shared__ unsigned short Ah[64][40];
  __shared__ unsigned short Al[64][40];
  const int tid = threadIdx.x, lane = tid & 63, wid = tid >> 6;
  const int mbase = blockIdx.x * 64;
  const int cg = blockIdx.y;
  const int srow = tid >> 2, kidx = (tid & 3) << 3;
  const float* rowptr;
  {
    const int grow = mbase + srow;
    if (amode) {
      const int t = grow >> 8, b = grow & 255;
      rowptr = t ? (Yp + ((size_t)(t - 1) * 256 + b) * IND) : (X1023 + (size_t)b * IND);
    } else {
      rowptr = A + (size_t)grow * K;
    }
  }
  const f32x4 z = {0.f, 0.f, 0.f, 0.f};
  f32x4 acc[4] = {z, z, z, z};
  const uint4* Wh4 = (const uint4*)Wh;
  const uint4* Wl4 = (const uint4*)Wl;
  for (int kk = 0; kk < KK; ++kk) {
    const int k0 = kk << 5;
    __syncthreads();
    float v[8];
#pragma unroll
    for (int j = 0; j < 8; ++j) {
      const int kg = k0 + kidx + j;
      v[j] = (kg < K) ? rowptr[kg] : 0.f;
    }
#pragma unroll
    for (int j = 0; j < 8; ++j) {
      const unsigned short h = f2bf(v[j]);
      Ah[srow][kidx + j] = h;
      Al[srow][kidx + j] = f2bf(v[j] - bf2f(h));
    }
    __syncthreads();
    const uint4 avh = *(const uint4*)&Ah[(wid << 4) + (lane & 15)][(lane >> 4) << 3];
    const uint4 avl = *(const uint4*)&Al[(wid << 4) + (lane & 15)][(lane >> 4) << 3];
#pragma unroll
    for (int tt = 0; tt < 4; ++tt) {
      const int bi = ((kk << 4) + (cg << 2) + tt) * 64 + lane;
      const uint4 bh = Wh4[bi], bl = Wl4[bi];
      acc[tt] = mfma16(avh, bh, acc[tt]);
      acc[tt] = mfma16(avh, bl, acc[tt]);
      acc[tt] = mfma16(avl, bh, acc[tt]);
    }
  }
#pragma unroll
  for (int tt = 0; tt < 4; ++tt) {
    const int col = ((cg << 2) + tt) * 16 + (lane & 15);
    const float bcol = bias[col];
#pragma unroll
    for (int r = 0; r < 4; ++r) {
      const int row = mbase + (wid << 4) + ((lane >> 4) << 2) + r;
      Pout[(size_t)row * 256 + col] = acc[tt][r] + bcol;
    }
  }
}

// ----------------------------------- scan ----------------------------------
// out_t = tanh(Pin_t + h_{t-1} U^T). Pout may equal Pin (in-place, proven) or
// be null (finals only). 16 rows per block; 8 waves x 2 col-tiles, U hi/lo
// register-resident (128 VGPR). h state in LDS as packed u32 (lo<<16|hi):
// reads 2x b128 per kk + v_perm unpack; writes 8x ds_write_b32 per thread
// (2-way bank = free). Raw lgkmcnt(0)+s_barrier; P_{t+1} register prefetch.
__device__ __forceinline__ void scan_body(
    const float* __restrict__ Pin, float* __restrict__ Pout,
    const unsigned short* __restrict__ Uh,
    const float* __restrict__ hinit, float* __restrict__ finals,
    const int r0) {
  __shared__ __align__(16) unsigned A2[2][16][260];
  const int tid = threadIdx.x, lane = tid & 63, wid = tid >> 6;
  const uint4* U4 = (const uint4*)Uh;  // lo component at +8192 uint4
  uint4 uf[2][2][8];                   // [hi/lo][tile][kk]
#pragma unroll
  for (int tt = 0; tt < 2; ++tt)
#pragma unroll
    for (int kk = 0; kk < 8; ++kk) {
      const int idx = ((kk << 4) + wid * 2 + tt) * 64 + lane;
      uf[0][tt][kk] = U4[idx];
      uf[1][tt][kk] = U4[idx + 8192];
    }
#pragma unroll
  for (int j = 0; j < 8; ++j) {  // init h_{-1}: 8 packed u32 per thread
    const int e = tid * 8 + j;
    const int row = e >> 8, col = e & 255;
    const float x = hinit ? hinit[((r0 + row) << 8) + col] : 0.f;
    A2[0][row][col] = packbf(x);
  }
  __syncthreads();
  const int rowl = (lane >> 4) << 2;
  const int col0 = wid * 32 + (lane & 15);
  const float* pin_base = Pin + (((size_t)(r0 + rowl)) << 8) + col0;
  float* pout_base = Pout ? (Pout + (((size_t)(r0 + rowl)) << 8) + col0) : (float*)0;
  float* fbase = finals ? (finals + (((size_t)(r0 + rowl)) << 8) + col0) : (float*)0;
  const f32x4 z = {0.f, 0.f, 0.f, 0.f};
  // prefetch P for t=0
  float pc[2][4];
#pragma unroll
  for (int tt = 0; tt < 2; ++tt)
#pragma unroll
    for (int r = 0; r < 4; ++r) pc[tt][r] = pin_base[tt * 16 + r * 256];
  for (int t = 0; t < TSTEPS; ++t) {
    const int cur = t & 1, nxt = cur ^ 1;
    // prefetch P for t+1 (stays in flight across the barrier)
    float pn[2][4];
    {
      const int tn = (t + 1 < TSTEPS) ? (t + 1) : t;
      const float* ptn = pin_base + (size_t)tn * 65536;
#pragma unroll
      for (int tt = 0; tt < 2; ++tt)
#pragma unroll
        for (int r = 0; r < 4; ++r) pn[tt][r] = ptn[tt * 16 + r * 256];
    }
    f32x4 hh[2] = {z, z}, hl[2] = {z, z}, lh[2] = {z, z};
#pragma unroll
    for (int kk = 0; kk < 8; ++kk) {
      const int koff = (kk << 5) + ((lane >> 4) << 3);
      const uint4 p0 = *(const uint4*)&A2[cur][lane & 15][koff];
      const uint4 p1v = *(const uint4*)&A2[cur][lane & 15][koff + 4];
      uint4 avh, avl;
      unpack_pair(p0, p1v, avh, avl);
      hh[0] = mfma16(avh, uf[0][0][kk], hh[0]);
      hh[1] = mfma16(avh, uf[0][1][kk], hh[1]);
      hl[0] = mfma16(avh, uf[1][0][kk], hl[0]);
      hl[1] = mfma16(avh, uf[1][1][kk], hl[1]);
      lh[0] = mfma16(avl, uf[0][0][kk], lh[0]);
      lh[1] = mfma16(avl, uf[0][1][kk], lh[1]);
    }
    float* pot = pout_base ? (pout_base + (size_t)t * 65536) : (float*)0;
#pragma unroll
    for (int tt = 0; tt < 2; ++tt) {
#pragma unroll
      for (int r = 0; r < 4; ++r) {
        const float av = (hh[tt][r] + hl[tt][r]) + lh[tt][r];
        const float x = ftanh(av + pc[tt][r]);
        if (pot) pot[tt * 16 + r * 256] = x;
        if (fbase && t == TSTEPS - 1) fbase[tt * 16 + r * 256] = x;
        A2[nxt][rowl + r][col0 + tt * 16] = packbf(x);
      }
    }
    // LDS exchange fence only: global stores + next-step prefetch loads stay
    // in flight across the barrier (no vmcnt(0) drain on the critical path).
    asm volatile("s_waitcnt lgkmcnt(0)\n\ts_barrier" ::: "memory");
#pragma unroll
    for (int tt = 0; tt < 2; ++tt)
#pragma unroll
      for (int r = 0; r < 4; ++r) pc[tt][r] = pn[tt][r];
  }
}

__global__ __launch_bounds__(512, 2) void scan_kernel(
    const float* __restrict__ Pin, float* __restrict__ Pout,
    const unsigned short* __restrict__ Uh,
    const float* __restrict__ hinit, float* __restrict__ finals) {
  scan_body(Pin, Pout, Uh, hinit, finals, blockIdx.x << 4);
}

// Two independent scans in one dispatch (e1 and d0 share no data; the only
// cross-block interaction is co-residency). bid<16 -> params A; else B.
__global__ __launch_bounds__(512, 2) void scan2_kernel(
    const float* __restrict__ PinA, float* __restrict__ PoutA,
    const unsigned short* __restrict__ UhA,
    const float* __restrict__ hinitA, float* __restrict__ finalsA,
    const float* __restrict__ PinB, float* __restrict__ PoutB,
    const unsigned short* __restrict__ UhB,
    const float* __restrict__ hinitB, float* __restrict__ finalsB) {
  const int bid = blockIdx.x;
  if (bid < 16) {
    scan_body(PinA, PoutA, UhA, hinitA, finalsA, bid << 4);
  } else {
    scan_body(PinB, PoutB, UhB, hinitB, finalsB, (bid - 16) << 4);
  }
}

// ------------------------------ head + softmax -----------------------------
__global__ __launch_bounds__(256) void head_kernel(
    const float* __restrict__ A, const unsigned short* __restrict__ Wh,
    const unsigned short* __restrict__ Wl, const float* __restrict__ biasp,
    float* __restrict__ out) {
  __shared__ unsigned short Ah[64][40];
  __shared__ unsigned short Al[64][40];
  const int tid = threadIdx.x, lane = tid & 63, wid = tid >> 6;
  const int mbase = blockIdx.x * 64;
  const int srow = tid >> 2, kidx = (tid & 3) << 3;
  const float* rowptr = A + (size_t)(mbase + srow) * 256;
  const f32x4 z = {0.f, 0.f, 0.f, 0.f};
  f32x4 acc[9] = {z, z, z, z, z, z, z, z, z};
  const uint4* Wh4 = (const uint4*)Wh;
  const uint4* Wl4 = (const uint4*)Wl;
  for (int kk = 0; kk < 8; ++kk) {
    const int k0 = kk << 5;
    __syncthreads();
#pragma unroll
    for (int j = 0; j < 8; ++j) {
      const float v = rowptr[k0 + kidx + j];
      const unsigned short h = f2bf(v);
      Ah[srow][kidx + j] = h;
      Al[srow][kidx + j] = f2bf(v - bf2f(h));
    }
    __syncthreads();
    const uint4 avh = *(const uint4*)&Ah[(wid << 4) + (lane & 15)][(lane >> 4) << 3];
    const uint4 avl = *(const uint4*)&Al[(wid << 4) + (lane & 15)][(lane >> 4) << 3];
#pragma unroll
    for (int tt = 0; tt < 9; ++tt) {
      const int bi = (kk * 9 + tt) * 64 + lane;
      const uint4 bh = Wh4[bi], bl = Wl4[bi];
      acc[tt] = mfma16(avh, bh, acc[tt]);
      acc[tt] = mfma16(avh, bl, acc[tt]);
      acc[tt] = mfma16(avl, bh, acc[tt]);
    }
  }
#pragma unroll
  for (int tt = 0; tt < 9; ++tt) {
    const float b = biasp[tt * 16 + (lane & 15)];
#pragma unroll
    for (int r = 0; r < 4; ++r) acc[tt][r] += b;
  }
  float lse[4];
#pragma unroll
  for (int r = 0; r < 4; ++r) {
    float m = acc[0][r];
#pragma unroll
    for (int tt = 1; tt < 9; ++tt) m = fmaxf(m, acc[tt][r]);
    m = fmaxf(m, __shfl_xor(m, 1));
    m = fmaxf(m, __shfl_xor(m, 2));
    m = fmaxf(m, __shfl_xor(m, 4));
    m = fmaxf(m, __shfl_xor(m, 8));
    float s = 0.f;
#pragma unroll
    for (int tt = 0; tt < 9; ++tt) s += __expf(acc[tt][r] - m);
    s += __shfl_xor(s, 1);
    s += __shfl_xor(s, 2);
    s += __shfl_xor(s, 4);
    s += __shfl_xor(s, 8);
    lse[r] = m + __logf(s);
  }
#pragma unroll
  for (int tt = 0; tt < 9; ++tt) {
    const int col = tt * 16 + (lane & 15);
    if (col < OUTD) {
#pragma unroll
      for (int r = 0; r < 4; ++r) {
        const int row = mbase + (wid << 4) + ((lane >> 4) << 2) + r;
        out[(size_t)row * OUTD + col] = acc[tt][r] - lse[r];
      }
    }
  }
}

// ========================= slow fallback (round 1) =========================
__device__ __forceinline__ void packWs(float* __restrict__ ws, const float* __restrict__ src,
                                       int e, int off, int K, int ncols) {
  const int le = e - off;
  const int m = le & 3;
  const int tt = le >> 2;
  const int j = tt % ncols;
  const int k4 = tt / ncols;
  const int k = k4 * 4 + m;
  ws[e] = (k < K) ? src[j * K + k] : 0.f;
}

__global__ void prep_slow(
    const float* __restrict__ eW0, const float* __restrict__ eH0,
    const float* __restrict__ eb_ih0, const float* __restrict__ eb_hh0,
    const float* __restrict__ eW1, const float* __restrict__ eH1,
    const float* __restrict__ eb_ih1, const float* __restrict__ eb_hh1,
    const float* __restrict__ dW0, const float* __restrict__ dH0,
    const float* __restrict__ db_ih0, const float* __restrict__ db_hh0,
    const float* __restrict__ dW1, const float* __restrict__ dH1,
    const float* __restrict__ db_ih1, const float* __restrict__ db_hh1,
    const float* __restrict__ linW, float* __restrict__ ws) {
  const int e = blockIdx.x * 256 + threadIdx.x;
  if (e >= WS_TOTAL_SLOW) return;
  if (e < OFF_EH0s)      packWs(ws, eW0, e, OFF_EW0s, IND, 256);
  else if (e < OFF_EW1s) packWs(ws, eH0, e, OFF_EH0s, 256, 256);
  else if (e < OFF_EH1s) packWs(ws, eW1, e, OFF_EW1s, 256, 256);
  else if (e < OFF_DW0s) packWs(ws, eH1, e, OFF_EH1s, 256, 256);
  else if (e < OFF_DH0s) packWs(ws, dW0, e, OFF_DW0s, IND, 256);
  else if (e < OFF_DW1s) packWs(ws, dH0, e, OFF_DH0s, 256, 256);
  else if (e < OFF_DH1s) packWs(ws, dW1, e, OFF_DW1s, 256, 256);
  else if (e < OFF_LWs)  packWs(ws, dH1, e, OFF_DH1s, 256, 256);
  else if (e < OFF_EB0s) packWs(ws, linW, e, OFF_LWs, 256, OUTD);
  else if (e < OFF_EB1s) { int j = e - OFF_EB0s; ws[e] = eb_ih0[j] + eb_hh0[j]; }
  else if (e < OFF_DB0s) { int j = e - OFF_EB1s; ws[e] = eb_ih1[j] + eb_hh1[j]; }
  else if (e < OFF_DB1s) { int j = e - OFF_DB0s; ws[e] = db_ih0[j] + db_hh0[j]; }
  else                   { int j = e - OFF_DB1s; ws[e] = db_ih1[j] + db_hh1[j]; }
}

__device__ __forceinline__ float dot4(const float4 a, const float4 b, float acc) {
  acc = fmaf(a.x, b.x, acc);
  acc = fmaf(a.y, b.y, acc);
  acc = fmaf(a.z, b.z, acc);
  acc = fmaf(a.w, b.w, acc);
  return acc;
}

__device__ __forceinline__ float2 layer_in(
    const float4* __restrict__ wih, const float4* __restrict__ whh,
    const float* __restrict__ x0, const float* __restrict__ x1,
    const float* __restrict__ h0, const float* __restrict__ h1,
    const float bias, const int tid) {
  float a0 = bias, a1 = bias;
#pragma unroll 4
  for (int k4 = 0; k4 < 33; ++k4) {
    const float4 w = wih[k4 * 256 + tid];
    a0 = dot4(*(const float4*)(x0 + k4 * 4), w, a0);
    a1 = dot4(*(const float4*)(x1 + k4 * 4), w, a1);
  }
#pragma unroll 4
  for (int k4 = 0; k4 < 64; ++k4) {
    const float4 w = whh[k4 * 256 + tid];
    a0 = dot4(*(const float4*)(h0 + k4 * 4), w, a0);
    a1 = dot4(*(const float4*)(h1 + k4 * 4), w, a1);
  }
  return make_float2(a0, a1);
}

__device__ __forceinline__ float2 layer_hh(
    const float4* __restrict__ wih, const float4* __restrict__ whh,
    const float* __restrict__ x0, const float* __restrict__ x1,
    const float* __restrict__ h0, const float* __restrict__ h1,
    const float bias, const int tid) {
  float a0 = bias, a1 = bias;
#pragma unroll 4
  for (int k4 = 0; k4 < 64; ++k4) {
    const float4 wi = wih[k4 * 256 + tid];
    const float4 wh = whh[k4 * 256 + tid];
    a0 = dot4(*(const float4*)(x0 + k4 * 4), wi, a0);
    a1 = dot4(*(const float4*)(x1 + k4 * 4), wi, a1);
    a0 = dot4(*(const float4*)(h0 + k4 * 4), wh, a0);
    a1 = dot4(*(const float4*)(h1 + k4 * 4), wh, a1);
  }
  return make_float2(a0, a1);
}

__global__ __launch_bounds__(256, 1) void rnn_slow(
    const float* __restrict__ X, const float* __restrict__ Y,
    const float* __restrict__ ws, const float* __restrict__ linb,
    float* __restrict__ out) {
  __shared__ __align__(16) float xb[2][132];
  __shared__ __align__(16) float h0s[2][256];
  __shared__ __align__(16) float h1s[2][256];
  __shared__ __align__(16) float lo[2][132];
  const int tid = threadIdx.x;
  const int r0 = blockIdx.x * 2;
  const float4* ew0 = (const float4*)(ws + OFF_EW0s);
  const float4* eh0 = (const float4*)(ws + OFF_EH0s);
  const float4* ew1 = (const float4*)(ws + OFF_EW1s);
  const float4* eh1 = (const float4*)(ws + OFF_EH1s);
  const float4* dw0 = (const float4*)(ws + OFF_DW0s);
  const float4* dh0 = (const float4*)(ws + OFF_DH0s);
  const float4* dw1 = (const float4*)(ws + OFF_DW1s);
  const float4* dh1 = (const float4*)(ws + OFF_DH1s);
  const float4* lw  = (const float4*)(ws + OFF_LWs);
  const float eb0v = ws[OFF_EB0s + tid];
  const float eb1v = ws[OFF_EB1s + tid];
  const float db0v = ws[OFF_DB0s + tid];
  const float db1v = ws[OFF_DB1s + tid];
  h0s[0][tid] = 0.f; h0s[1][tid] = 0.f;
  h1s[0][tid] = 0.f; h1s[1][tid] = 0.f;
  __syncthreads();
  for (int t = 0; t < TSTEPS; ++t) {
    {
      const int r = tid / 132, i = tid - r * 132;
      xb[r][i] = (i < IND) ? X[((size_t)t * BATCH + r0 + r) * IND + i] : 0.f;
      if (tid < 8) {
        const int i2 = tid + 124;
        xb[1][i2] = (i2 < IND) ? X[((size_t)t * BATCH + r0 + 1) * IND + i2] : 0.f;
      }
    }
    __syncthreads();
    const float2 a = layer_in(ew0, eh0, xb[0], xb[1], h0s[0], h0s[1], eb0v, tid);
    const float n0a = ftanh(a.x), n0b = ftanh(a.y);
    __syncthreads();
    h0s[0][tid] = n0a; h0s[1][tid] = n0b;
    __syncthreads();
    const float2 b = layer_hh(ew1, eh1, h0s[0], h0s[1], h1s[0], h1s[1], eb1v, tid);
    const float n1a = ftanh(b.x), n1b = ftanh(b.y);
    __syncthreads();
    h1s[0][tid] = n1a; h1s[1][tid] = n1b;
    __syncthreads();
  }
  for (int t = 0; t < TSTEPS; ++t) {
    const float* xbase = (t == 0) ? (X + (size_t)TSTEPS * BATCH * IND)
                                  : (Y + (size_t)(t - 1) * BATCH * IND);
    {
      const int r = tid / 132, i = tid - r * 132;
      xb[r][i] = (i < IND) ? xbase[(size_t)(r0 + r) * IND + i] : 0.f;
      if (tid < 8) {
        const int i2 = tid + 124;
        xb[1][i2] = (i2 < IND) ? xbase[(size_t)(r0 + 1) * IND + i2] : 0.f;
      }
    }
    __syncthreads();
    const float2 a = layer_in(dw0, dh0, xb[0], xb[1], h0s[0], h0s[1], db0v, tid);
    const float n0a = ftanh(a.x), n0b = ftanh(a.y);
    __syncthreads();
    h0s[0][tid] = n0a; h0s[1][tid] = n0b;
    __syncthreads();
    const float2 b = layer_hh(dw1, dh1, h0s[0], h0s[1], h1s[0], h1s[1], db1v, tid);
    const float n1a = ftanh(b.x), n1b = ftanh(b.y);
    __syncthreads();
    h1s[0][tid] = n1a; h1s[1][tid] = n1b;
    __syncthreads();
    if (tid < OUTD) {
      float c0 = linb[tid], c1 = linb[tid];
#pragma unroll 4
      for (int k4 = 0; k4 < 64; ++k4) {
        const float4 w = lw[k4 * OUTD + tid];
        c0 = dot4(*(const float4*)&h1s[0][k4 * 4], w, c0);
        c1 = dot4(*(const float4*)&h1s[1][k4 * 4], w, c1);
      }
      lo[0][tid] = c0;
      lo[1][tid] = c1;
    }
    __syncthreads();
    const int wid = tid >> 6, lane = tid & 63;
    if (wid < 2) {
      float m = -3.0e38f;
      for (int o = lane; o < OUTD; o += 64) m = fmaxf(m, lo[wid][o]);
#pragma unroll
      for (int off = 32; off > 0; off >>= 1) m = fmaxf(m, __shfl_xor(m, off, 64));
      float s = 0.f;
      for (int o = lane; o < OUTD; o += 64) s += __expf(lo[wid][o] - m);
#pragma unroll
      for (int off = 32; off > 0; off >>= 1) s += __shfl_xor(s, off, 64);
      const float lse = m + __logf(s);
      float* op = out + ((size_t)t * BATCH + r0 + wid) * OUTD;
      for (int o = lane; o < OUTD; o += 64) op[o] = lo[wid][o] - lse;
    }
    __syncthreads();
  }
}

// ================================ launcher =================================
extern "C" void kernel_launch(void* const* d_in, const int* in_sizes, int n_in,
                              void* d_out, int out_size, void* d_ws, size_t ws_size,
                              hipStream_t stream) {
  const float* X      = (const float*)d_in[0];
  const float* Y      = (const float*)d_in[1];
  const float* eW0    = (const float*)d_in[2];
  const float* eH0    = (const float*)d_in[3];
  const float* eb_ih0 = (const float*)d_in[4];
  const float* eb_hh0 = (const float*)d_in[5];
  const float* eW1    = (const float*)d_in[6];
  const float* eH1    = (const float*)d_in[7];
  const float* eb_ih1 = (const float*)d_in[8];
  const float* eb_hh1 = (const float*)d_in[9];
  const float* dW0    = (const float*)d_in[10];
  const float* dH0    = (const float*)d_in[11];
  const float* db_ih0 = (const float*)d_in[12];
  const float* db_hh0 = (const float*)d_in[13];
  const float* dW1    = (const float*)d_in[14];
  const float* dH1    = (const float*)d_in[15];
  const float* db_ih1 = (const float*)d_in[16];
  const float* db_hh1 = (const float*)d_in[17];
  const float* linW   = (const float*)d_in[18];
  const float* linb   = (const float*)d_in[19];
  float* out = (float*)d_out;

  if (ws_size >= TOTAL_WS) {
    float* buf0 = (float*)d_ws;
    float* buf1 = (float*)((char*)d_ws + SB);
    unsigned short* pk = (unsigned short*)((char*)d_ws + PKB);
    float* bfin = (float*)((char*)d_ws + BFB);
    float* be0 = bfin, *be1 = bfin + 256, *bd0 = bfin + 512, *bd1 = bfin + 768;
    float* blin = bfin + 1024;
    float* fin0 = bfin + FIN0;
    float* fin1 = bfin + FIN1;
    const float* X1023 = X + (size_t)TSTEPS * BATCH * IND;

    prep_pack<<<2005, 256, 0, stream>>>(eW0, eH0, eb_ih0, eb_hh0, eW1, eH1, eb_ih1,
                                        eb_hh1, dW0, dH0, db_ih0, db_hh0, dW1, dH1,
                                        db_ih1, db_hh1, linW, linb, pk, bfin);
    // encoder layer 0: P_e0 -> buf0; scan in-place (out0 in buf0), fin0
    gemm_proj<<<dim3(MTOT / 64, 4), 256, 0, stream>>>(
        X, nullptr, nullptr, 0, IND, 5, pk + EW0, pk + EW0 + 40960, be0, buf0);
    scan_kernel<<<16, 512, 0, stream>>>(buf0, buf0, pk + UE0, nullptr, fin0);
    // P_e1 = out0 @ W_e1^T -> buf1 ; P_d0 (X[-1],Y inputs) -> buf0
    gemm_proj<<<dim3(MTOT / 64, 4), 256, 0, stream>>>(
        buf0, nullptr, nullptr, 0, 256, 8, pk + EW1, pk + EW1 + 65536, be1, buf1);
    gemm_proj<<<dim3(MTOT / 64, 4), 256, 0, stream>>>(
        nullptr, X1023, Y, 1, IND, 5, pk + DW0, pk + DW0 + 40960, bd0, buf0);
    // concurrent: [A] enc L1 scan on buf1 (finals only, fin1)
    //             [B] dec L0 scan on buf0 in-place (init fin0)
    scan2_kernel<<<32, 512, 0, stream>>>(
        buf1, nullptr, pk + UE1, nullptr, fin1,
        buf0, buf0,   pk + UD0, fin0,   nullptr);
    // decoder layer 1: P_d1 = outd0 @ W_d1^T -> buf1; scan in-place (init fin1)
    gemm_proj<<<dim3(MTOT / 64, 4), 256, 0, stream>>>(
        buf0, nullptr, nullptr, 0, 256, 8, pk + DW1, pk + DW1 + 65536, bd1, buf1);
    scan_kernel<<<16, 512, 0, stream>>>(buf1, buf1, pk + UD1, fin1, nullptr);
    // linear head + log_softmax
    head_kernel<<<MTOT / 64, 256, 0, stream>>>(buf1, pk + LINP, pk + LINP + 36864,
                                               blin, out);
  } else {
    float* ws = (float*)d_ws;
    prep_slow<<<(WS_TOTAL_SLOW + 255) / 256, 256, 0, stream>>>(
        eW0, eH0, eb_ih0, eb_hh0, eW1, eH1, eb_ih1, eb_hh1,
        dW0, dH0, db_ih0, db_hh0, dW1, dH1, db_ih1, db_hh1, linW, ws);
    rnn_slow<<<128, 256, 0, stream>>>(X, Y, ws, linb, out);
  }
}

// Round 11
// 7526.662 us; speedup vs baseline: 2.9938x; 1.0808x over previous
//
#include <hip/hip_runtime.h>
#include <cstddef>

// ---------------------------------------------------------------------------
// RNN_Reverser round 8: single-pass input projection.
// Round-7 measured: 8134 us. scan2 merge confirmed (2002 us for 2 concurrent
// scans, -1.5 ms); packed-u32 LDS neutral (conflicts/time unchanged). Residual
// analysis: the four gemm_proj dispatches cost ~450-560 us each vs ~85 us
// ideal -- the blockIdx.y=4 split makes 4 blocks re-read the same 64 A-rows
// (4x A over-fetch, 4x staging). This round: gemm_proj computes all 16
// col-tiles per block (acc[16], 64 VGPR) in ONE pass; grid (MTOT/64).
// Weight traffic unchanged (L2-resident); A-stream and LDS staging drop 4x.
// Scans untouched: scan-e0 | scan2[e1||d0] | scan-d1 (round-7 proven).
// All matmuls split-bf16 (hh+hl+lh) for fp32-like precision.
// ---------------------------------------------------------------------------

typedef __attribute__((ext_vector_type(8))) short short8;
typedef __attribute__((ext_vector_type(4))) float f32x4;

namespace {
constexpr int TSTEPS = 1023;
constexpr int BATCH = 256;
constexpr int IND = 131;
constexpr int OUTD = 131;
constexpr int MTOT = TSTEPS * BATCH;  // 261888

// fast path ws layout (bytes)
constexpr size_t SB = (size_t)MTOT * 256 * 4;  // 268,173,312 one P buffer
// pack region: ushort offsets
constexpr int UE0 = 0;        // each U pack: hi 65536 + lo 65536
constexpr int UE1 = 131072;
constexpr int UD0 = 262144;
constexpr int UD1 = 393216;
constexpr int EW0 = 524288;   // proj K=131: hi 40960 + lo 40960
constexpr int DW0 = 606208;
constexpr int EW1 = 688128;   // proj K=256: hi 65536 + lo 65536
constexpr int DW1 = 819200;
constexpr int LINP = 950272;  // lin: hi 36864 + lo 36864
constexpr int PK_USH = 1024000;
constexpr size_t PKB = 2 * SB;                   // pack base (bytes)
constexpr size_t BFB = PKB + 2 * (size_t)PK_USH; // bias/finals float region
constexpr int FIN0 = 1168;
constexpr int FIN1 = 1168 + 65536;
constexpr size_t TOTAL_WS = BFB + (size_t)(1168 + 2 * 65536) * 4;  // 538,923,584

// slow path (round 1) float offsets
constexpr int OFF_EW0s = 0, OFF_EH0s = 33792, OFF_EW1s = 99328, OFF_EH1s = 164864;
constexpr int OFF_DW0s = 230400, OFF_DH0s = 264192, OFF_DW1s = 329728, OFF_DH1s = 395264;
constexpr int OFF_LWs = 460800, OFF_EB0s = 494336, OFF_EB1s = 494592;
constexpr int OFF_DB0s = 494848, OFF_DB1s = 495104;
constexpr int WS_TOTAL_SLOW = 495360;
}  // namespace

__device__ __forceinline__ unsigned short f2bf(float x) {
  unsigned u = __float_as_uint(x);
  u += 0x7fffu + ((u >> 16) & 1u);
  return (unsigned short)(u >> 16);
}
__device__ __forceinline__ float bf2f(unsigned short h) {
  return __uint_as_float(((unsigned)h) << 16);
}
__device__ __forceinline__ unsigned packbf(float x) {
  const unsigned short h = f2bf(x);
  const unsigned short l = f2bf(x - bf2f(h));
  return ((unsigned)l << 16) | (unsigned)h;
}
__device__ __forceinline__ float ftanh(float x) {
  const float ax = fabsf(x);
  const float e = __expf(-2.f * ax);
  const float t = __fdividef(1.f - e, 1.f + e);
  return copysignf(t, x);
}
__device__ __forceinline__ f32x4 mfma16(uint4 a, uint4 b, f32x4 c) {
  return __builtin_amdgcn_mfma_f32_16x16x32_bf16(
      __builtin_bit_cast(short8, a), __builtin_bit_cast(short8, b), c, 0, 0, 0);
}
// unpack 8 packed (lo<<16|hi) u32 -> hi-frag / lo-frag (round-4 proven)
__device__ __forceinline__ void unpack_pair(uint4 p0, uint4 p1,
                                            uint4& avh, uint4& avl) {
  avh.x = __builtin_amdgcn_perm(p0.y, p0.x, 0x05040100u);
  avh.y = __builtin_amdgcn_perm(p0.w, p0.z, 0x05040100u);
  avh.z = __builtin_amdgcn_perm(p1.y, p1.x, 0x05040100u);
  avh.w = __builtin_amdgcn_perm(p1.w, p1.z, 0x05040100u);
  avl.x = __builtin_amdgcn_perm(p0.y, p0.x, 0x07060302u);
  avl.y = __builtin_amdgcn_perm(p0.w, p0.z, 0x07060302u);
  avl.z = __builtin_amdgcn_perm(p1.y, p1.x, 0x07060302u);
  avl.w = __builtin_amdgcn_perm(p1.w, p1.z, 0x07060302u);
}

// ------------------------------- prep (fast) -------------------------------
// Packs all weights as hi/lo bf16 in MFMA B-fragment order:
//   frag element (kk, tile, lane, j) <- W[tile*16 + (lane&15)][kk*32 + (lane>>4)*8 + j]
__global__ void prep_pack(
    const float* __restrict__ eW0, const float* __restrict__ eH0,
    const float* __restrict__ eb_ih0, const float* __restrict__ eb_hh0,
    const float* __restrict__ eW1, const float* __restrict__ eH1,
    const float* __restrict__ eb_ih1, const float* __restrict__ eb_hh1,
    const float* __restrict__ dW0, const float* __restrict__ dH0,
    const float* __restrict__ db_ih0, const float* __restrict__ db_hh0,
    const float* __restrict__ dW1, const float* __restrict__ dH1,
    const float* __restrict__ db_ih1, const float* __restrict__ db_hh1,
    const float* __restrict__ linW, const float* __restrict__ linb,
    unsigned short* __restrict__ pk, float* __restrict__ bfin) {
  const int e = blockIdx.x * 256 + threadIdx.x;
  if (e >= 513168) return;
  if (e < 262144) {  // recurrent U matrices (256x256)
    const int um = e >> 16, le = e & 65535;
    const int j = le & 7, lane = (le >> 3) & 63, tile = (le >> 9) & 15, kk = le >> 13;
    const int n = tile * 16 + (lane & 15), k = kk * 32 + ((lane >> 4) << 3) + j;
    const float* U = (um == 0) ? eH0 : (um == 1) ? eH1 : (um == 2) ? dH0 : dH1;
    const float x = U[n * 256 + k];
    const unsigned short h = f2bf(x);
    const int base = um * 131072;
    pk[base + le] = h;
    pk[base + 65536 + le] = f2bf(x - bf2f(h));
  } else if (e < 344064) {  // eW0 / dW0 (256x131, K pad 160, KK=5)
    const bool isD = (e >= 303104);
    const int e2 = e - (isD ? 303104 : 262144);
    const int j = e2 & 7, lane = (e2 >> 3) & 63, tile = (e2 >> 9) & 15, kk = e2 >> 13;
    const int n = tile * 16 + (lane & 15), k = kk * 32 + ((lane >> 4) << 3) + j;
    const float* W = isD ? dW0 : eW0;
    const float x = (k < IND) ? W[n * IND + k] : 0.f;
    const unsigned short h = f2bf(x);
    const int base = isD ? DW0 : EW0;
    pk[base + e2] = h;
    pk[base + 40960 + e2] = f2bf(x - bf2f(h));
  } else if (e < 475136) {  // eW1 / dW1 (256x256, KK=8)
    const bool isD = (e >= 409600);
    const int e2 = e - (isD ? 409600 : 344064);
    const int j = e2 & 7, lane = (e2 >> 3) & 63, tile = (e2 >> 9) & 15, kk = e2 >> 13;
    const int n = tile * 16 + (lane & 15), k = kk * 32 + ((lane >> 4) << 3) + j;
    const float* W = isD ? dW1 : eW1;
    const float x = W[n * 256 + k];
    const unsigned short h = f2bf(x);
    const int base = isD ? DW1 : EW1;
    pk[base + e2] = h;
    pk[base + 65536 + e2] = f2bf(x - bf2f(h));
  } else if (e < 512000) {  // lin_W (131x256 -> 144 cols pad, 9 tiles, KK=8)
    const int e2 = e - 475136;
    const int kk = e2 / 4608;
    const int rem = e2 - kk * 4608;
    const int t9 = rem >> 9, le = rem & 511;
    const int j = le & 7, lane = le >> 3;
    const int n = t9 * 16 + (lane & 15), k = kk * 32 + ((lane >> 4) << 3) + j;
    const float x = (n < OUTD) ? linW[n * 256 + k] : 0.f;
    const unsigned short h = f2bf(x);
    pk[LINP + e2] = h;
    pk[LINP + 36864 + e2] = f2bf(x - bf2f(h));
  } else {  // combined biases + padded lin bias
    const int e3 = e - 512000;
    if (e3 < 256) bfin[e3] = eb_ih0[e3] + eb_hh0[e3];
    else if (e3 < 512) { const int j = e3 - 256; bfin[e3] = eb_ih1[j] + eb_hh1[j]; }
    else if (e3 < 768) { const int j = e3 - 512; bfin[e3] = db_ih0[j] + db_hh0[j]; }
    else if (e3 < 1024){ const int j = e3 - 768; bfin[e3] = db_ih1[j] + db_hh1[j]; }
    else { const int j = e3 - 1024; bfin[e3] = (j < OUTD) ? linb[j] : -1e30f; }
  }
}

// ------------------------- batched input projection ------------------------
// P[m][0..255] = A[m][0..K) @ W^T + bias ; grid (MTOT/64), block 256.
// Single-pass: each wave computes 16 rows x all 16 col-tiles (acc[16]).
// A staged once per block (was 4x via blockIdx.y); weights stream from L2.
__global__ __launch_bounds__(256) void gemm_proj(
    const float* __restrict__ A, const float* __restrict__ X1023,
    const float* __restrict__ Yp, const int amode, const int K, const int KK,
    const unsigned short* __restrict__ Wh, const unsigned short* __restrict__ Wl,
    const float* __restrict__ bias, float* __restrict__ Pout) {
  __shared__ unsigned short Ah[64][40];
  __shared__ unsigned short Al[64][40];
  const int tid = threadIdx.x, lane = tid & 63, wid = tid >> 6;
  const int mbase = blockIdx.x * 64;
  const int srow = tid >> 2, kidx = (tid & 3) << 3;
  const float* rowptr;
  {
    const int grow = mbase + srow;
    if (amode) {
      const int t = grow >> 8, b = grow & 255;
      rowptr = t ? (Yp + ((size_t)(t - 1) * 256 + b) * IND) : (X1023 + (size_t)b * IND);
    } else {
      rowptr = A + (size_t)grow * K;
    }
  }
  const f32x4 z = {0.f, 0.f, 0.f, 0.f};
  f32x4 acc[16] = {z, z, z, z, z, z, z, z, z, z, z, z, z, z, z, z};
  const uint4* Wh4 = (const uint4*)Wh;
  const uint4* Wl4 = (const uint4*)Wl;
  for (int kk = 0; kk < KK; ++kk) {
    const int k0 = kk << 5;
    __syncthreads();
    float v[8];
#pragma unroll
    for (int j = 0; j < 8; ++j) {
      const int kg = k0 + kidx + j;
      v[j] = (kg < K) ? rowptr[kg] : 0.f;
    }
#pragma unroll
    for (int j = 0; j < 8; ++j) {
      const unsigned short h = f2bf(v[j]);
      Ah[srow][kidx + j] = h;
      Al[srow][kidx + j] = f2bf(v[j] - bf2f(h));
    }
    __syncthreads();
    const uint4 avh = *(const uint4*)&Ah[(wid << 4) + (lane & 15)][(lane >> 4) << 3];
    const uint4 avl = *(const uint4*)&Al[(wid << 4) + (lane & 15)][(lane >> 4) << 3];
#pragma unroll
    for (int tt = 0; tt < 16; ++tt) {
      const int bi = ((kk << 4) + tt) * 64 + lane;
      const uint4 bh = Wh4[bi], bl = Wl4[bi];
      acc[tt] = mfma16(avh, bh, acc[tt]);
      acc[tt] = mfma16(avh, bl, acc[tt]);
      acc[tt] = mfma16(avl, bh, acc[tt]);
    }
  }
#pragma unroll
  for (int tt = 0; tt < 16; ++tt) {
    const int col = tt * 16 + (lane & 15);
    const float bcol = bias[col];
#pragma unroll
    for (int r = 0; r < 4; ++r) {
      const int row = mbase + (wid << 4) + ((lane >> 4) << 2) + r;
      Pout[(size_t)row * 256 + col] = acc[tt][r] + bcol;
    }
  }
}

// ----------------------------------- scan ----------------------------------
// out_t = tanh(Pin_t + h_{t-1} U^T). Pout may equal Pin (in-place, proven) or
// be null (finals only). 16 rows per block; 8 waves x 2 col-tiles, U hi/lo
// register-resident (128 VGPR). h state in LDS as packed u32 (lo<<16|hi):
// reads 2x b128 per kk + v_perm unpack; writes 8x ds_write_b32 per thread.
// Raw lgkmcnt(0)+s_barrier; P_{t+1} register prefetch.
__device__ __forceinline__ void scan_body(
    const float* __restrict__ Pin, float* __restrict__ Pout,
    const unsigned short* __restrict__ Uh,
    const float* __restrict__ hinit, float* __restrict__ finals,
    const int r0) {
  __shared__ __align__(16) unsigned A2[2][16][260];
  const int tid = threadIdx.x, lane = tid & 63, wid = tid >> 6;
  const uint4* U4 = (const uint4*)Uh;  // lo component at +8192 uint4
  uint4 uf[2][2][8];                   // [hi/lo][tile][kk]
#pragma unroll
  for (int tt = 0; tt < 2; ++tt)
#pragma unroll
    for (int kk = 0; kk < 8; ++kk) {
      const int idx = ((kk << 4) + wid * 2 + tt) * 64 + lane;
      uf[0][tt][kk] = U4[idx];
      uf[1][tt][kk] = U4[idx + 8192];
    }
#pragma unroll
  for (int j = 0; j < 8; ++j) {  // init h_{-1}: 8 packed u32 per thread
    const int e = tid * 8 + j;
    const int row = e >> 8, col = e & 255;
    const float x = hinit ? hinit[((r0 + row) << 8) + col] : 0.f;
    A2[0][row][col] = packbf(x);
  }
  __syncthreads();
  const int rowl = (lane >> 4) << 2;
  const int col0 = wid * 32 + (lane & 15);
  const float* pin_base = Pin + (((size_t)(r0 + rowl)) << 8) + col0;
  float* pout_base = Pout ? (Pout + (((size_t)(r0 + rowl)) << 8) + col0) : (float*)0;
  float* fbase = finals ? (finals + (((size_t)(r0 + rowl)) << 8) + col0) : (float*)0;
  const f32x4 z = {0.f, 0.f, 0.f, 0.f};
  // prefetch P for t=0
  float pc[2][4];
#pragma unroll
  for (int tt = 0; tt < 2; ++tt)
#pragma unroll
    for (int r = 0; r < 4; ++r) pc[tt][r] = pin_base[tt * 16 + r * 256];
  for (int t = 0; t < TSTEPS; ++t) {
    const int cur = t & 1, nxt = cur ^ 1;
    // prefetch P for t+1 (stays in flight across the barrier)
    float pn[2][4];
    {
      const int tn = (t + 1 < TSTEPS) ? (t + 1) : t;
      const float* ptn = pin_base + (size_t)tn * 65536;
#pragma unroll
      for (int tt = 0; tt < 2; ++tt)
#pragma unroll
        for (int r = 0; r < 4; ++r) pn[tt][r] = ptn[tt * 16 + r * 256];
    }
    f32x4 hh[2] = {z, z}, hl[2] = {z, z}, lh[2] = {z, z};
#pragma unroll
    for (int kk = 0; kk < 8; ++kk) {
      const int koff = (kk << 5) + ((lane >> 4) << 3);
      const uint4 p0 = *(const uint4*)&A2[cur][lane & 15][koff];
      const uint4 p1v = *(const uint4*)&A2[cur][lane & 15][koff + 4];
      uint4 avh, avl;
      unpack_pair(p0, p1v, avh, avl);
      hh[0] = mfma16(avh, uf[0][0][kk], hh[0]);
      hh[1] = mfma16(avh, uf[0][1][kk], hh[1]);
      hl[0] = mfma16(avh, uf[1][0][kk], hl[0]);
      hl[1] = mfma16(avh, uf[1][1][kk], hl[1]);
      lh[0] = mfma16(avl, uf[0][0][kk], lh[0]);
      lh[1] = mfma16(avl, uf[0][1][kk], lh[1]);
    }
    float* pot = pout_base ? (pout_base + (size_t)t * 65536) : (float*)0;
#pragma unroll
    for (int tt = 0; tt < 2; ++tt) {
#pragma unroll
      for (int r = 0; r < 4; ++r) {
        const float av = (hh[tt][r] + hl[tt][r]) + lh[tt][r];
        const float x = ftanh(av + pc[tt][r]);
        if (pot) pot[tt * 16 + r * 256] = x;
        if (fbase && t == TSTEPS - 1) fbase[tt * 16 + r * 256] = x;
        A2[nxt][rowl + r][col0 + tt * 16] = packbf(x);
      }
    }
    // LDS exchange fence only: global stores + next-step prefetch loads stay
    // in flight across the barrier (no vmcnt(0) drain on the critical path).
    asm volatile("s_waitcnt lgkmcnt(0)\n\ts_barrier" ::: "memory");
#pragma unroll
    for (int tt = 0; tt < 2; ++tt)
#pragma unroll
      for (int r = 0; r < 4; ++r) pc[tt][r] = pn[tt][r];
  }
}

__global__ __launch_bounds__(512, 2) void scan_kernel(
    const float* __restrict__ Pin, float* __restrict__ Pout,
    const unsigned short* __restrict__ Uh,
    const float* __restrict__ hinit, float* __restrict__ finals) {
  scan_body(Pin, Pout, Uh, hinit, finals, blockIdx.x << 4);
}

// Two independent scans in one dispatch (e1 and d0 share no data; the only
// cross-block interaction is co-residency). bid<16 -> params A; else B.
__global__ __launch_bounds__(512, 2) void scan2_kernel(
    const float* __restrict__ PinA, float* __restrict__ PoutA,
    const unsigned short* __restrict__ UhA,
    const float* __restrict__ hinitA, float* __restrict__ finalsA,
    const float* __restrict__ PinB, float* __restrict__ PoutB,
    const unsigned short* __restrict__ UhB,
    const float* __restrict__ hinitB, float* __restrict__ finalsB) {
  const int bid = blockIdx.x;
  if (bid < 16) {
    scan_body(PinA, PoutA, UhA, hinitA, finalsA, bid << 4);
  } else {
    scan_body(PinB, PoutB, UhB, hinitB, finalsB, (bid - 16) << 4);
  }
}

// ------------------------------ head + softmax -----------------------------
__global__ __launch_bounds__(256) void head_kernel(
    const float* __restrict__ A, const unsigned short* __restrict__ Wh,
    const unsigned short* __restrict__ Wl, const float* __restrict__ biasp,
    float* __restrict__ out) {
  __shared__ unsigned short Ah[64][40];
  __shared__ unsigned short Al[64][40];
  const int tid = threadIdx.x, lane = tid & 63, wid = tid >> 6;
  const int mbase = blockIdx.x * 64;
  const int srow = tid >> 2, kidx = (tid & 3) << 3;
  const float* rowptr = A + (size_t)(mbase + srow) * 256;
  const f32x4 z = {0.f, 0.f, 0.f, 0.f};
  f32x4 acc[9] = {z, z, z, z, z, z, z, z, z};
  const uint4* Wh4 = (const uint4*)Wh;
  const uint4* Wl4 = (const uint4*)Wl;
  for (int kk = 0; kk < 8; ++kk) {
    const int k0 = kk << 5;
    __syncthreads();
#pragma unroll
    for (int j = 0; j < 8; ++j) {
      const float v = rowptr[k0 + kidx + j];
      const unsigned short h = f2bf(v);
      Ah[srow][kidx + j] = h;
      Al[srow][kidx + j] = f2bf(v - bf2f(h));
    }
    __syncthreads();
    const uint4 avh = *(const uint4*)&Ah[(wid << 4) + (lane & 15)][(lane >> 4) << 3];
    const uint4 avl = *(const uint4*)&Al[(wid << 4) + (lane & 15)][(lane >> 4) << 3];
#pragma unroll
    for (int tt = 0; tt < 9; ++tt) {
      const int bi = (kk * 9 + tt) * 64 + lane;
      const uint4 bh = Wh4[bi], bl = Wl4[bi];
      acc[tt] = mfma16(avh, bh, acc[tt]);
      acc[tt] = mfma16(avh, bl, acc[tt]);
      acc[tt] = mfma16(avl, bh, acc[tt]);
    }
  }
#pragma unroll
  for (int tt = 0; tt < 9; ++tt) {
    const float b = biasp[tt * 16 + (lane & 15)];
#pragma unroll
    for (int r = 0; r < 4; ++r) acc[tt][r] += b;
  }
  float lse[4];
#pragma unroll
  for (int r = 0; r < 4; ++r) {
    float m = acc[0][r];
#pragma unroll
    for (int tt = 1; tt < 9; ++tt) m = fmaxf(m, acc[tt][r]);
    m = fmaxf(m, __shfl_xor(m, 1));
    m = fmaxf(m, __shfl_xor(m, 2));
    m = fmaxf(m, __shfl_xor(m, 4));
    m = fmaxf(m, __shfl_xor(m, 8));
    float s = 0.f;
#pragma unroll
    for (int tt = 0; tt < 9; ++tt) s += __expf(acc[tt][r] - m);
    s += __shfl_xor(s, 1);
    s += __shfl_xor(s, 2);
    s += __shfl_xor(s, 4);
    s += __shfl_xor(s, 8);
    lse[r] = m + __logf(s);
  }
#pragma unroll
  for (int tt = 0; tt < 9; ++tt) {
    const int col = tt * 16 + (lane & 15);
    if (col < OUTD) {
#pragma unroll
      for (int r = 0; r < 4; ++r) {
        const int row = mbase + (wid << 4) + ((lane >> 4) << 2) + r;
        out[(size_t)row * OUTD + col] = acc[tt][r] - lse[r];
      }
    }
  }
}

// ========================= slow fallback (round 1) =========================
__device__ __forceinline__ void packWs(float* __restrict__ ws, const float* __restrict__ src,
                                       int e, int off, int K, int ncols) {
  const int le = e - off;
  const int m = le & 3;
  const int tt = le >> 2;
  const int j = tt % ncols;
  const int k4 = tt / ncols;
  const int k = k4 * 4 + m;
  ws[e] = (k < K) ? src[j * K + k] : 0.f;
}

__global__ void prep_slow(
    const float* __restrict__ eW0, const float* __restrict__ eH0,
    const float* __restrict__ eb_ih0, const float* __restrict__ eb_hh0,
    const float* __restrict__ eW1, const float* __restrict__ eH1,
    const float* __restrict__ eb_ih1, const float* __restrict__ eb_hh1,
    const float* __restrict__ dW0, const float* __restrict__ dH0,
    const float* __restrict__ db_ih0, const float* __restrict__ db_hh0,
    const float* __restrict__ dW1, const float* __restrict__ dH1,
    const float* __restrict__ db_ih1, const float* __restrict__ db_hh1,
    const float* __restrict__ linW, float* __restrict__ ws) {
  const int e = blockIdx.x * 256 + threadIdx.x;
  if (e >= WS_TOTAL_SLOW) return;
  if (e < OFF_EH0s)      packWs(ws, eW0, e, OFF_EW0s, IND, 256);
  else if (e < OFF_EW1s) packWs(ws, eH0, e, OFF_EH0s, 256, 256);
  else if (e < OFF_EH1s) packWs(ws, eW1, e, OFF_EW1s, 256, 256);
  else if (e < OFF_DW0s) packWs(ws, eH1, e, OFF_EH1s, 256, 256);
  else if (e < OFF_DH0s) packWs(ws, dW0, e, OFF_DW0s, IND, 256);
  else if (e < OFF_DW1s) packWs(ws, dH0, e, OFF_DH0s, 256, 256);
  else if (e < OFF_DH1s) packWs(ws, dW1, e, OFF_DW1s, 256, 256);
  else if (e < OFF_LWs)  packWs(ws, dH1, e, OFF_DH1s, 256, 256);
  else if (e < OFF_EB0s) packWs(ws, linW, e, OFF_LWs, 256, OUTD);
  else if (e < OFF_EB1s) { int j = e - OFF_EB0s; ws[e] = eb_ih0[j] + eb_hh0[j]; }
  else if (e < OFF_DB0s) { int j = e - OFF_EB1s; ws[e] = eb_ih1[j] + eb_hh1[j]; }
  else if (e < OFF_DB1s) { int j = e - OFF_DB0s; ws[e] = db_ih0[j] + db_hh0[j]; }
  else                   { int j = e - OFF_DB1s; ws[e] = db_ih1[j] + db_hh1[j]; }
}

__device__ __forceinline__ float dot4(const float4 a, const float4 b, float acc) {
  acc = fmaf(a.x, b.x, acc);
  acc = fmaf(a.y, b.y, acc);
  acc = fmaf(a.z, b.z, acc);
  acc = fmaf(a.w, b.w, acc);
  return acc;
}

__device__ __forceinline__ float2 layer_in(
    const float4* __restrict__ wih, const float4* __restrict__ whh,
    const float* __restrict__ x0, const float* __restrict__ x1,
    const float* __restrict__ h0, const float* __restrict__ h1,
    const float bias, const int tid) {
  float a0 = bias, a1 = bias;
#pragma unroll 4
  for (int k4 = 0; k4 < 33; ++k4) {
    const float4 w = wih[k4 * 256 + tid];
    a0 = dot4(*(const float4*)(x0 + k4 * 4), w, a0);
    a1 = dot4(*(const float4*)(x1 + k4 * 4), w, a1);
  }
#pragma unroll 4
  for (int k4 = 0; k4 < 64; ++k4) {
    const float4 w = whh[k4 * 256 + tid];
    a0 = dot4(*(const float4*)(h0 + k4 * 4), w, a0);
    a1 = dot4(*(const float4*)(h1 + k4 * 4), w, a1);
  }
  return make_float2(a0, a1);
}

__device__ __forceinline__ float2 layer_hh(
    const float4* __restrict__ wih, const float4* __restrict__ whh,
    const float* __restrict__ x0, const float* __restrict__ x1,
    const float* __restrict__ h0, const float* __restrict__ h1,
    const float bias, const int tid) {
  float a0 = bias, a1 = bias;
#pragma unroll 4
  for (int k4 = 0; k4 < 64; ++k4) {
    const float4 wi = wih[k4 * 256 + tid];
    const float4 wh = whh[k4 * 256 + tid];
    a0 = dot4(*(const float4*)(x0 + k4 * 4), wi, a0);
    a1 = dot4(*(const float4*)(x1 + k4 * 4), wi, a1);
    a0 = dot4(*(const float4*)(h0 + k4 * 4), wh, a0);
    a1 = dot4(*(const float4*)(h1 + k4 * 4), wh, a1);
  }
  return make_float2(a0, a1);
}

__global__ __launch_bounds__(256, 1) void rnn_slow(
    const float* __restrict__ X, const float* __restrict__ Y,
    const float* __restrict__ ws, const float* __restrict__ linb,
    float* __restrict__ out) {
  __shared__ __align__(16) float xb[2][132];
  __shared__ __align__(16) float h0s[2][256];
  __shared__ __align__(16) float h1s[2][256];
  __shared__ __align__(16) float lo[2][132];
  const int tid = threadIdx.x;
  const int r0 = blockIdx.x * 2;
  const float4* ew0 = (const float4*)(ws + OFF_EW0s);
  const float4* eh0 = (const float4*)(ws + OFF_EH0s);
  const float4* ew1 = (const float4*)(ws + OFF_EW1s);
  const float4* eh1 = (const float4*)(ws + OFF_EH1s);
  const float4* dw0 = (const float4*)(ws + OFF_DW0s);
  const float4* dh0 = (const float4*)(ws + OFF_DH0s);
  const float4* dw1 = (const float4*)(ws + OFF_DW1s);
  const float4* dh1 = (const float4*)(ws + OFF_DH1s);
  const float4* lw  = (const float4*)(ws + OFF_LWs);
  const float eb0v = ws[OFF_EB0s + tid];
  const float eb1v = ws[OFF_EB1s + tid];
  const float db0v = ws[OFF_DB0s + tid];
  const float db1v = ws[OFF_DB1s + tid];
  h0s[0][tid] = 0.f; h0s[1][tid] = 0.f;
  h1s[0][tid] = 0.f; h1s[1][tid] = 0.f;
  __syncthreads();
  for (int t = 0; t < TSTEPS; ++t) {
    {
      const int r = tid / 132, i = tid - r * 132;
      xb[r][i] = (i < IND) ? X[((size_t)t * BATCH + r0 + r) * IND + i] : 0.f;
      if (tid < 8) {
        const int i2 = tid + 124;
        xb[1][i2] = (i2 < IND) ? X[((size_t)t * BATCH + r0 + 1) * IND + i2] : 0.f;
      }
    }
    __syncthreads();
    const float2 a = layer_in(ew0, eh0, xb[0], xb[1], h0s[0], h0s[1], eb0v, tid);
    const float n0a = ftanh(a.x), n0b = ftanh(a.y);
    __syncthreads();
    h0s[0][tid] = n0a; h0s[1][tid] = n0b;
    __syncthreads();
    const float2 b = layer_hh(ew1, eh1, h0s[0], h0s[1], h1s[0], h1s[1], eb1v, tid);
    const float n1a = ftanh(b.x), n1b = ftanh(b.y);
    __syncthreads();
    h1s[0][tid] = n1a; h1s[1][tid] = n1b;
    __syncthreads();
  }
  for (int t = 0; t < TSTEPS; ++t) {
    const float* xbase = (t == 0) ? (X + (size_t)TSTEPS * BATCH * IND)
                                  : (Y + (size_t)(t - 1) * BATCH * IND);
    {
      const int r = tid / 132, i = tid - r * 132;
      xb[r][i] = (i < IND) ? xbase[(size_t)(r0 + r) * IND + i] : 0.f;
      if (tid < 8) {
        const int i2 = tid + 124;
        xb[1][i2] = (i2 < IND) ? xbase[(size_t)(r0 + 1) * IND + i2] : 0.f;
      }
    }
    __syncthreads();
    const float2 a = layer_in(dw0, dh0, xb[0], xb[1], h0s[0], h0s[1], db0v, tid);
    const float n0a = ftanh(a.x), n0b = ftanh(a.y);
    __syncthreads();
    h0s[0][tid] = n0a; h0s[1][tid] = n0b;
    __syncthreads();
    const float2 b = layer_hh(dw1, dh1, h0s[0], h0s[1], h1s[0], h1s[1], db1v, tid);
    const float n1a = ftanh(b.x), n1b = ftanh(b.y);
    __syncthreads();
    h1s[0][tid] = n1a; h1s[1][tid] = n1b;
    __syncthreads();
    if (tid < OUTD) {
      float c0 = linb[tid], c1 = linb[tid];
#pragma unroll 4
      for (int k4 = 0; k4 < 64; ++k4) {
        const float4 w = lw[k4 * OUTD + tid];
        c0 = dot4(*(const float4*)&h1s[0][k4 * 4], w, c0);
        c1 = dot4(*(const float4*)&h1s[1][k4 * 4], w, c1);
      }
      lo[0][tid] = c0;
      lo[1][tid] = c1;
    }
    __syncthreads();
    const int wid = tid >> 6, lane = tid & 63;
    if (wid < 2) {
      float m = -3.0e38f;
      for (int o = lane; o < OUTD; o += 64) m = fmaxf(m, lo[wid][o]);
#pragma unroll
      for (int off = 32; off > 0; off >>= 1) m = fmaxf(m, __shfl_xor(m, off, 64));
      float s = 0.f;
      for (int o = lane; o < OUTD; o += 64) s += __expf(lo[wid][o] - m);
#pragma unroll
      for (int off = 32; off > 0; off >>= 1) s += __shfl_xor(s, off, 64);
      const float lse = m + __logf(s);
      float* op = out + ((size_t)t * BATCH + r0 + wid) * OUTD;
      for (int o = lane; o < OUTD; o += 64) op[o] = lo[wid][o] - lse;
    }
    __syncthreads();
  }
}

// ================================ launcher =================================
extern "C" void kernel_launch(void* const* d_in, const int* in_sizes, int n_in,
                              void* d_out, int out_size, void* d_ws, size_t ws_size,
                              hipStream_t stream) {
  const float* X      = (const float*)d_in[0];
  const float* Y      = (const float*)d_in[1];
  const float* eW0    = (const float*)d_in[2];
  const float* eH0    = (const float*)d_in[3];
  const float* eb_ih0 = (const float*)d_in[4];
  const float* eb_hh0 = (const float*)d_in[5];
  const float* eW1    = (const float*)d_in[6];
  const float* eH1    = (const float*)d_in[7];
  const float* eb_ih1 = (const float*)d_in[8];
  const float* eb_hh1 = (const float*)d_in[9];
  const float* dW0    = (const float*)d_in[10];
  const float* dH0    = (const float*)d_in[11];
  const float* db_ih0 = (const float*)d_in[12];
  const float* db_hh0 = (const float*)d_in[13];
  const float* dW1    = (const float*)d_in[14];
  const float* dH1    = (const float*)d_in[15];
  const float* db_ih1 = (const float*)d_in[16];
  const float* db_hh1 = (const float*)d_in[17];
  const float* linW   = (const float*)d_in[18];
  const float* linb   = (const float*)d_in[19];
  float* out = (float*)d_out;

  if (ws_size >= TOTAL_WS) {
    float* buf0 = (float*)d_ws;
    float* buf1 = (float*)((char*)d_ws + SB);
    unsigned short* pk = (unsigned short*)((char*)d_ws + PKB);
    float* bfin = (float*)((char*)d_ws + BFB);
    float* be0 = bfin, *be1 = bfin + 256, *bd0 = bfin + 512, *bd1 = bfin + 768;
    float* blin = bfin + 1024;
    float* fin0 = bfin + FIN0;
    float* fin1 = bfin + FIN1;
    const float* X1023 = X + (size_t)TSTEPS * BATCH * IND;

    prep_pack<<<2005, 256, 0, stream>>>(eW0, eH0, eb_ih0, eb_hh0, eW1, eH1, eb_ih1,
                                        eb_hh1, dW0, dH0, db_ih0, db_hh0, dW1, dH1,
                                        db_ih1, db_hh1, linW, linb, pk, bfin);
    // encoder layer 0: P_e0 -> buf0; scan in-place (out0 in buf0), fin0
    gemm_proj<<<MTOT / 64, 256, 0, stream>>>(
        X, nullptr, nullptr, 0, IND, 5, pk + EW0, pk + EW0 + 40960, be0, buf0);
    scan_kernel<<<16, 512, 0, stream>>>(buf0, buf0, pk + UE0, nullptr, fin0);
    // P_e1 = out0 @ W_e1^T -> buf1 ; P_d0 (X[-1],Y inputs) -> buf0
    gemm_proj<<<MTOT / 64, 256, 0, stream>>>(
        buf0, nullptr, nullptr, 0, 256, 8, pk + EW1, pk + EW1 + 65536, be1, buf1);
    gemm_proj<<<MTOT / 64, 256, 0, stream>>>(
        nullptr, X1023, Y, 1, IND, 5, pk + DW0, pk + DW0 + 40960, bd0, buf0);
    // concurrent: [A] enc L1 scan on buf1 (finals only, fin1)
    //             [B] dec L0 scan on buf0 in-place (init fin0)
    scan2_kernel<<<32, 512, 0, stream>>>(
        buf1, nullptr, pk + UE1, nullptr, fin1,
        buf0, buf0,   pk + UD0, fin0,   nullptr);
    // decoder layer 1: P_d1 = outd0 @ W_d1^T -> buf1; scan in-place (init fin1)
    gemm_proj<<<MTOT / 64, 256, 0, stream>>>(
        buf0, nullptr, nullptr, 0, 256, 8, pk + DW1, pk + DW1 + 65536, bd1, buf1);
    scan_kernel<<<16, 512, 0, stream>>>(buf1, buf1, pk + UD1, fin1, nullptr);
    // linear head + log_softmax
    head_kernel<<<MTOT / 64, 256, 0, stream>>>(buf1, pk + LINP, pk + LINP + 36864,
                                               blin, out);
  } else {
    float* ws = (float*)d_ws;
    prep_slow<<<(WS_TOTAL_SLOW + 255) / 256, 256, 0, stream>>>(
        eW0, eH0, eb_ih0, eb_hh0, eW1, eH1, eb_ih1, eb_hh1,
        dW0, dH0, db_ih0, db_hh0, dW1, dH1, db_ih1, db_hh1, linW, ws);
    rnn_slow<<<128, 256, 0, stream>>>(X, Y, ws, linb, out);
  }
}